// Round 12
// baseline (712.900 us; speedup 1.0000x reference)
//
#include <hip/hip_runtime.h>

#define DD 128

typedef __attribute__((ext_vector_type(8))) short bh8;       // 8 bf16 (as i16 bits)
typedef __attribute__((ext_vector_type(8))) unsigned short us8;
typedef __attribute__((ext_vector_type(4))) float f4;
typedef unsigned int u32;
typedef unsigned short u16;

__device__ __forceinline__ u16 tob(float f) {           // fp32 -> bf16 RNE
  u32 u = __builtin_bit_cast(u32, f);
  u += 0x7FFFu + ((u >> 16) & 1u);
  return (u16)(u >> 16);
}
__device__ __forceinline__ float fb(u16 h) { return __builtin_bit_cast(float, (u32)h << 16); }

// ================= CSR build (real edges only; self-loops analytic) =================

__global__ __launch_bounds__(256) void init_counts_k(int* cn, int* ce, int N, int E) {
  int g = blockIdx.x * blockDim.x + threadIdx.x;
  if (g < E) ce[g] = 0;
  if (g < N) cn[g] = 0;
}

// ---- parallel hierarchical exclusive scan (chunks of 1024) ----

__global__ __launch_bounds__(256) void scan_partials_k(const int* __restrict__ cn, const int* __restrict__ ce,
                                                       int* part, int NCHN, int N, int NCHE, int E) {
  __shared__ int red[256];
  int b = blockIdx.x, tid = threadIdx.x;
  const int* cnt = (b < NCHN) ? cn : ce;
  int n = (b < NCHN) ? N : E;
  int base = ((b < NCHN) ? b : (b - NCHN)) << 10;
  int i0 = base + tid * 4;
  int s = 0;
  #pragma unroll
  for (int j = 0; j < 4; ++j) { int i = i0 + j; if (i < n) s += cnt[i]; }
  red[tid] = s; __syncthreads();
  for (int off = 128; off > 0; off >>= 1) {
    if (tid < off) red[tid] += red[tid + off];
    __syncthreads();
  }
  if (tid == 0) part[b] = red[0];
}

__device__ __forceinline__ int blk_excl_scan(int s, int tid, int* sums) {
  sums[tid] = s; __syncthreads();
  for (int off = 1; off < 256; off <<= 1) {
    int t = (tid >= off) ? sums[tid - off] : 0;
    __syncthreads();
    sums[tid] += t;
    __syncthreads();
  }
  int ex = sums[tid] - s;
  __syncthreads();
  return ex;
}

// scan_apply with inlined chunk-prefix (part[] holds RAW chunk sums)
__global__ __launch_bounds__(256) void scan_apply_k(const int* __restrict__ cn, const int* __restrict__ ce,
                                                    const int* __restrict__ part,
                                                    int* offs_n, int* offs_e,
                                                    int NCHN, int N, int NCHE, int E) {
  __shared__ int sums[256];
  __shared__ int base_s;
  int b = blockIdx.x, tid = threadIdx.x;
  const bool isN = b < NCHN;
  const int* cnt = isN ? cn : ce;
  int* offs = isN ? offs_n : offs_e;
  int n = isN ? N : E;
  int nch = isN ? NCHN : NCHE;
  int c = isN ? b : b - NCHN;
  const int* pbase = isN ? part : part + NCHN;
  {
    int v = (tid < nch) ? pbase[tid] : 0;
    int ex = blk_excl_scan(v, tid, sums);
    if (tid == c) base_s = ex;
  }
  __syncthreads();
  int base = (c << 10);
  int i0 = base + tid * 4;
  int v[4]; int s = 0;
  #pragma unroll
  for (int j = 0; j < 4; ++j) { int i = i0 + j; int t = (i < n) ? cnt[i] : 0; v[j] = t; s += t; }
  int ex = blk_excl_scan(s, tid, sums);
  int run = base_s + ex;
  #pragma unroll
  for (int j = 0; j < 4; ++j) { int i = i0 + j; if (i < n) offs[i] = run; run += v[j]; }
  if (tid == 255 && base + 1024 >= n) offs[n] = run;
}

__global__ __launch_bounds__(256) void fill_deg_k(const int* __restrict__ offs_n, const int* __restrict__ offs_e,
                                                  float* Dn_inv, float* De_inv,
                                                  int* cur_be, int* cur_bn,
                                                  int N, int E, int NBE, int NBN) {
  int g = blockIdx.x * blockDim.x + threadIdx.x;
  if (g < E) {
    int b = offs_e[g], e = offs_e[g + 1];
    De_inv[g] = (e > b) ? 1.0f / (float)(e - b) : 0.0f;
  }
  if (g < N) {
    int b = offs_n[g], e = offs_n[g + 1];
    Dn_inv[g] = 1.0f / (float)(e - b + 1);   // +1 self loop
  }
  if (g < NBE) {
    int r1 = (g + 1) * 32; if (r1 > E) r1 = E;
    int o0 = offs_e[g * 32], o1 = offs_e[r1];
    int C = o1 - o0, base = 8 * o0;
    #pragma unroll
    for (int k = 0; k < 8; ++k) cur_be[g * 8 + k] = base + k * C;
  }
  if (g < NBN) {
    int r1 = (g + 1) * 32; if (r1 > N) r1 = N;
    int o0 = offs_n[g * 32], o1 = offs_n[r1];
    int C = o1 - o0, base = 8 * o0;
    #pragma unroll
    for (int k = 0; k < 8; ++k) cur_bn[g * 8 + k] = base + k * C;
  }
}

__global__ __launch_bounds__(256) void partition2_k(const int* __restrict__ ni, const int* __restrict__ ei,
                                                    int* cur_be, int* cur_bn,
                                                    u32* __restrict__ SE, u32* __restrict__ SN, int nnz) {
  int xcd;
  asm volatile("s_getreg_b32 %0, hwreg(HW_REG_XCC_ID)" : "=s"(xcd));
  xcd &= 7;
  int stride = gridDim.x * blockDim.x;
  for (int j = blockIdx.x * blockDim.x + threadIdx.x; j < nnz; j += stride) {
    int n = ni[j], e = ei[j];
    int pe = atomicAdd(&cur_be[(e >> 5) * 8 + xcd], 1);
    SE[pe] = ((u32)(e & 31) << 17) | (u32)n;
    int pn = atomicAdd(&cur_bn[(n >> 5) * 8 + xcd], 1);
    SN[pn] = ((u32)(n & 31) << 17) | (u32)e;
  }
}

__device__ __forceinline__ void scatter_body(const u32* __restrict__ S, const int* __restrict__ offs,
                                             const int* __restrict__ cur_b,
                                             int* __restrict__ list, int nRows, int b, int tid, int* cur) {
  const int i0 = b << 5;
  if (tid < 32) {
    int row = i0 + tid;
    cur[tid] = (row < nRows) ? offs[row] : 0;
  }
  __syncthreads();
  int r1 = i0 + 32; if (r1 > nRows) r1 = nRows;
  const int o0 = offs[i0];
  const int C = offs[r1] - o0;
  #pragma unroll 1
  for (int k = 0; k < 8; ++k) {
    int sbeg = 8 * o0 + k * C;
    int send = cur_b[b * 8 + k];
    for (int i = sbeg + tid; i < send; i += 256) {
      u32 v = S[i];
      int pos = atomicAdd(&cur[v >> 17], 1);
      list[pos] = (int)(v & 0x1FFFFu);
    }
  }
}

__global__ __launch_bounds__(256) void scatter_both_k(const u32* SE, const int* offs_e, const int* cur_be,
                                                      int* listE, int E, int NBE,
                                                      const u32* SN, const int* offs_n, const int* cur_bn,
                                                      int* listN, int N) {
  __shared__ int cur[32];
  int b = blockIdx.x, tid = threadIdx.x;
  if (b < NBE) scatter_body(SE, offs_e, cur_be, listE, E, b, tid, cur);
  else         scatter_body(SN, offs_n, cur_bn, listN, N, b - NBE, tid, cur);
}

// ================= gathers (width 256, bf16, split-wave: 16B/lane) =================

__device__ __forceinline__ void acc8(float a[8], us8 v) {
  #pragma unroll
  for (int j = 0; j < 8; ++j) a[j] += fb(v[j]);
}

template<int SPLIT>
__global__ __launch_bounds__(256) void gather_edge_k(const u16* __restrict__ srcb,
                                                     const int* __restrict__ offs, const int* __restrict__ list,
                                                     const float* __restrict__ De_inv,
                                                     const float* __restrict__ b1, const float* __restrict__ b2,
                                                     const float* __restrict__ alphap,
                                                     u16* __restrict__ e_fullb,
                                                     float* __restrict__ d2a, float* __restrict__ d2b, int E) {
  const int wave = threadIdx.x >> 6, lane = threadIdx.x & 63;
  const int row = blockIdx.x * 4 + wave;
  if (row >= E) return;
  const int half = lane >> 5, cl = lane & 31;
  const int c8 = cl * 8;
  const int beg = offs[row], end = offs[row + 1];
  float a0[8] = {0,0,0,0,0,0,0,0}, a1[8] = {0,0,0,0,0,0,0,0};
  int i = beg + half;
  for (; i + 2 < end; i += 4) {
    us8 v0 = *(const us8*)&srcb[(size_t)list[i] * 256 + c8];
    us8 v1 = *(const us8*)&srcb[(size_t)list[i + 2] * 256 + c8];
    acc8(a0, v0); acc8(a1, v1);
  }
  if (i < end) acc8(a0, *(const us8*)&srcb[(size_t)list[i] * 256 + c8]);
  float s[8];
  #pragma unroll
  for (int j = 0; j < 8; ++j) s[j] = a0[j] + a1[j];
  #pragma unroll
  for (int j = 0; j < 8; ++j) s[j] += __shfl_xor(s[j], 32);
  if (half == 0) {
    float sc = De_inv[row];
    const float* bp = (c8 < 128) ? (b1 + c8) : (b2 + c8 - 128);
    float4 bt0 = *(const float4*)bp;
    float4 bt1 = *(const float4*)(bp + 4);
    float bb[8] = {bt0.x, bt0.y, bt0.z, bt0.w, bt1.x, bt1.y, bt1.z, bt1.w};
    float al = *alphap;
    us8 ob;
    float ov[8];
    #pragma unroll
    for (int j = 0; j < 8; ++j) {
      float v = sc * s[j] + bb[j];
      v = (v >= 0.f) ? v : al * v;
      ov[j] = v; ob[j] = tob(v);
    }
    *(us8*)&e_fullb[(size_t)row * 256 + c8] = ob;
    if constexpr (SPLIT == 1) {
      float* dp = (c8 < 128) ? &d2a[(size_t)row * DD + c8] : &d2b[(size_t)row * DD + c8 - 128];
      float4 w0 = {ov[0], ov[1], ov[2], ov[3]};
      float4 w1 = {ov[4], ov[5], ov[6], ov[7]};
      *(float4*)dp = w0;
      *(float4*)(dp + 4) = w1;
    }
  }
}

__global__ __launch_bounds__(256) void gather_node_k(const u16* __restrict__ e_fullb,
                                                     const u16* __restrict__ tb,
                                                     const int* __restrict__ offs, const int* __restrict__ list,
                                                     const float* __restrict__ Dn_inv,
                                                     const float* __restrict__ b1, const float* __restrict__ b2,
                                                     const float* __restrict__ alphap,
                                                     u16* __restrict__ dstb, int N) {
  const int wave = threadIdx.x >> 6, lane = threadIdx.x & 63;
  const int row = blockIdx.x * 4 + wave;
  if (row >= N) return;
  const int half = lane >> 5, cl = lane & 31;
  const int c8 = cl * 8;
  const int beg = offs[row], end = offs[row + 1];
  float a0[8] = {0,0,0,0,0,0,0,0}, a1[8] = {0,0,0,0,0,0,0,0};
  int i = beg + half;
  for (; i + 2 < end; i += 4) {
    us8 v0 = *(const us8*)&e_fullb[(size_t)list[i] * 256 + c8];
    us8 v1 = *(const us8*)&e_fullb[(size_t)list[i + 2] * 256 + c8];
    acc8(a0, v0); acc8(a1, v1);
  }
  if (i < end) acc8(a0, *(const us8*)&e_fullb[(size_t)list[i] * 256 + c8]);
  float s[8];
  #pragma unroll
  for (int j = 0; j < 8; ++j) s[j] = a0[j] + a1[j];
  #pragma unroll
  for (int j = 0; j < 8; ++j) s[j] += __shfl_xor(s[j], 32);
  if (half == 0) {
    us8 tv = *(const us8*)&tb[(size_t)row * 256 + c8];
    const float* bp = (c8 < 128) ? (b1 + c8) : (b2 + c8 - 128);
    float4 bt0 = *(const float4*)bp;
    float4 bt1 = *(const float4*)(bp + 4);
    float bb[8] = {bt0.x, bt0.y, bt0.z, bt0.w, bt1.x, bt1.y, bt1.z, bt1.w};
    float al = *alphap;
    float sc = Dn_inv[row];
    us8 ob;
    #pragma unroll
    for (int j = 0; j < 8; ++j) {
      float sv = fb(tv[j]) + bb[j];
      sv = (sv >= 0.f) ? sv : al * sv;
      ob[j] = tob(sc * (sv + s[j]));
    }
    *(us8*)&dstb[(size_t)row * 256 + c8] = ob;
  }
}

// ================= weight prep =================

struct WPtrs { const float* p[16]; };

__global__ __launch_bounds__(256) void prep_w_k(WPtrs wp, char* dst) {
  int m = blockIdx.x >> 3, s = blockIdx.x & 7;
  const float* W = wp.p[m];
  int t = threadIdx.x;
  int n = t & 127;
  int k0 = s * 16 + (t >> 7) * 8;
  us8 vhi, vlo;
  #pragma unroll
  for (int j = 0; j < 8; ++j) {
    float x = W[(size_t)(k0 + j) * DD + n];
    u32 ux = __builtin_bit_cast(u32, x);
    float hf = __builtin_bit_cast(float, ux & 0xFFFF0000u);
    float l = x - hf;
    vhi[j] = (u16)(ux >> 16);
    vlo[j] = (u16)(__builtin_bit_cast(u32, l) >> 16);
  }
  char* base = dst + (size_t)m * 65536;
  int byte = n * 256 + k0 * 2;
  byte ^= (n & 7) << 4;
  *(us8*)(base + byte) = vhi;
  *(us8*)(base + 32768 + byte) = vlo;
}

// ================= MFMA machinery =================

__device__ __forceinline__ void stage_w(const char* gsrc, char* lds, int tid) {
  int wave = tid >> 6, lane = tid & 63;
  #pragma unroll
  for (int i = 0; i < 16; ++i) {
    int off = (wave * 16 + i) * 1024;
    __builtin_amdgcn_global_load_lds(
        (const __attribute__((address_space(1))) u32*)(gsrc + off + lane * 16),
        (__attribute__((address_space(3))) u32*)(lds + off), 16, 0, 0);
  }
}

__device__ __forceinline__ void split8(const float vs[8], bh8& hi, bh8& lo) {
  #pragma unroll
  for (int j = 0; j < 8; ++j) {
    u32 u = __builtin_bit_cast(u32, vs[j]);
    float hf = __builtin_bit_cast(float, u & 0xFFFF0000u);
    float l = vs[j] - hf;
    hi[j] = (short)(u >> 16);
    lo[j] = (short)(__builtin_bit_cast(u32, l) >> 16);
  }
}

__device__ __forceinline__ void mk_afrag(const float* rowp, int koff, bh8& hi, bh8& lo) {
  float4 v0 = *(const float4*)(rowp + koff);
  float4 v1 = *(const float4*)(rowp + koff + 4);
  float vs[8] = {v0.x, v0.y, v0.z, v0.w, v1.x, v1.y, v1.z, v1.w};
  split8(vs, hi, lo);
}

// fp32-A split-3 path
__device__ __forceinline__ void mfma_ks(const bh8& ahi, const bh8& alo, const char* Wl,
                                        int ks, int lane, f4 acc[8]) {
  const int koff0 = (lane >> 4) * 8;
  const int k2 = (ks * 32 + koff0) * 2;
  #pragma unroll
  for (int cb = 0; cb < 8; ++cb) {
    int n = cb * 16 + (lane & 15);
    int byte = (n * 256 + k2) ^ ((n & 7) << 4);
    bh8 bhiF = *(const bh8*)(Wl + byte);
    bh8 bloF = *(const bh8*)(Wl + 32768 + byte);
    acc[cb] = __builtin_amdgcn_mfma_f32_16x16x32_bf16(ahi, bhiF, acc[cb], 0, 0, 0);
    acc[cb] = __builtin_amdgcn_mfma_f32_16x16x32_bf16(ahi, bloF, acc[cb], 0, 0, 0);
    acc[cb] = __builtin_amdgcn_mfma_f32_16x16x32_bf16(alo, bhiF, acc[cb], 0, 0, 0);
  }
}

// bf16-A exact path (2 MFMA)
__device__ __forceinline__ void mfma_ks_bf(const bh8& a, const char* Wl,
                                           int ks, int lane, f4 acc[8]) {
  const int koff0 = (lane >> 4) * 8;
  const int k2 = (ks * 32 + koff0) * 2;
  #pragma unroll
  for (int cb = 0; cb < 8; ++cb) {
    int n = cb * 16 + (lane & 15);
    int byte = (n * 256 + k2) ^ ((n & 7) << 4);
    bh8 bhiF = *(const bh8*)(Wl + byte);
    bh8 bloF = *(const bh8*)(Wl + 32768 + byte);
    acc[cb] = __builtin_amdgcn_mfma_f32_16x16x32_bf16(a, bhiF, acc[cb], 0, 0, 0);
    acc[cb] = __builtin_amdgcn_mfma_f32_16x16x32_bf16(a, bloF, acc[cb], 0, 0, 0);
  }
}

__device__ __forceinline__ void mfma_passS(const float* __restrict__ A, size_t astride, int acoff,
                                           const char* Wl, int rbase, int nrows, int lane, f4 acc[8]) {
  int r = rbase + (lane & 15);
  if (r >= nrows) r = nrows - 1;
  const float* rowp = A + (size_t)r * astride + acoff;
  const int koff0 = (lane >> 4) * 8;
  #pragma unroll
  for (int ks = 0; ks < 4; ++ks) {
    bh8 ahi, alo;
    mk_afrag(rowp, ks * 32 + koff0, ahi, alo);
    mfma_ks(ahi, alo, Wl, ks, lane, acc);
  }
}

__device__ __forceinline__ void mfma_passB(const u16* __restrict__ A, size_t astride, int acoff,
                                           const char* Wl, int rbase, int nrows, int lane, f4 acc[8]) {
  int r = rbase + (lane & 15);
  if (r >= nrows) r = nrows - 1;
  const u16* rowp = A + (size_t)r * astride + acoff;
  const int koff0 = (lane >> 4) * 8;
  #pragma unroll
  for (int ks = 0; ks < 4; ++ks) {
    bh8 a = __builtin_bit_cast(bh8, *(const us8*)(rowp + ks * 32 + koff0));
    mfma_ks_bf(a, Wl, ks, lane, acc);
  }
}

struct AFragB { bh8 a[4]; };

__device__ __forceinline__ void load_afragB(const u16* __restrict__ A, size_t astride, int acoff,
                                            int rbase, int nrows, int lane, AFragB& f) {
  int r = rbase + (lane & 15);
  if (r >= nrows) r = nrows - 1;
  const u16* rowp = A + (size_t)r * astride + acoff;
  const int koff0 = (lane >> 4) * 8;
  #pragma unroll
  for (int ks = 0; ks < 4; ++ks)
    f.a[ks] = __builtin_bit_cast(bh8, *(const us8*)(rowp + ks * 32 + koff0));
}

__device__ __forceinline__ void mfma_pass_fragB(const AFragB& f, const char* Wl, int lane, f4 acc[8]) {
  #pragma unroll
  for (int ks = 0; ks < 4; ++ks) mfma_ks_bf(f.a[ks], Wl, ks, lane, acc);
}

// ---- LDS T-tile (64 rows x 128 bf16, XOR-swizzled; base = Tb pointer) ----

__device__ __forceinline__ void acc_to_T(f4 acc[8], const float* bias, float al,
                                         char* Tb, int wave, int lane) {
  const int cidx = lane & 15;
  float b8[8];
  #pragma unroll
  for (int cb = 0; cb < 8; ++cb) b8[cb] = bias[cb * 16 + cidx];
  #pragma unroll
  for (int q = 0; q < 4; ++q) {
    int row = wave * 16 + (lane >> 4) * 4 + q;
    #pragma unroll
    for (int cb = 0; cb < 8; ++cb) {
      float v = acc[cb][q] + b8[cb];
      v = (v >= 0.f) ? v : al * v;
      int byte = (row * 256 + (cb * 16 + cidx) * 2) ^ ((row & 7) << 4);
      *(u16*)(Tb + byte) = tob(v);
    }
  }
}

__device__ __forceinline__ void load_fT(const char* Tb, int wave, int lane, AFragB& f) {
  const int row = wave * 16 + (lane & 15);
  const int koff0 = (lane >> 4) * 8;
  #pragma unroll
  for (int ks = 0; ks < 4; ++ks) {
    int byte = (row * 256 + (ks * 32 + koff0) * 2) ^ ((row & 7) << 4);
    f.a[ks] = __builtin_bit_cast(bh8, *(const us8*)(Tb + byte));
  }
}

// MODE 0: raw; MODE 1: +bias +prelu.  OBF: write bf16 instead of fp32.
template<int MODE, int OBF>
__device__ __forceinline__ void epilogueS(f4 acc[8], const float* bias, const float* alphap,
                                          void* outp, size_t ostride, int ocoff,
                                          int rbase, int nrows, int lane) {
  float al = 0.f;
  if constexpr (MODE == 1) al = *alphap;
  const int cidx = lane & 15;
  int rq = rbase + (lane >> 4) * 4;
  float b8[8];
  if constexpr (MODE == 1) {
    #pragma unroll
    for (int cb = 0; cb < 8; ++cb) b8[cb] = bias[cb * 16 + cidx];
  }
  #pragma unroll
  for (int q = 0; q < 4; ++q) {
    int row = rq + q;
    if (row < nrows) {
      #pragma unroll
      for (int cb = 0; cb < 8; ++cb) {
        float v = acc[cb][q];
        if constexpr (MODE == 1) { v += b8[cb]; v = (v >= 0.f) ? v : al * v; }
        if constexpr (OBF == 1) {
          u16* op = (u16*)outp + (size_t)row * ostride + ocoff + cidx;
          op[cb * 16] = tob(v);
        } else {
          float* op = (float*)outp + (size_t)row * ostride + ocoff + cidx;
          op[cb * 16] = v;
        }
      }
    }
  }
}

#define ACC_ZERO(acc) { _Pragma("unroll") for (int cb = 0; cb < 8; ++cb) acc[cb] = {0.f, 0.f, 0.f, 0.f}; }

// ================= GEMM kernels =================

// combo: blocks [0,NT) = GEMM1 (x@W0 | xx@W4 -> tb bf16, fp32-A split-3);
//        blocks [NT, NT+HB) = histogram (grid-stride)
__global__ __launch_bounds__(256, 2) void combo1_k(const float* __restrict__ x, const char* W0,
                                                   const float* __restrict__ xx, const char* W4,
                                                   u16* __restrict__ tb, int nrows, int NT,
                                                   const int* __restrict__ ni, const int* __restrict__ ei,
                                                   int* cn, int* ce, int nnz) {
  __shared__ char Wl[65536];
  if ((int)blockIdx.x < NT) {
    const int wave = threadIdx.x >> 6, lane = threadIdx.x & 63;
    const int rbase = blockIdx.x * 64 + wave * 16;
    f4 acc[8];
    stage_w(W0, Wl, threadIdx.x);
    __syncthreads();
    ACC_ZERO(acc);
    mfma_passS(x, DD, 0, Wl, rbase, nrows, lane, acc);
    epilogueS<0, 1>(acc, nullptr, nullptr, tb, 256, 0, rbase, nrows, lane);
    __syncthreads();
    stage_w(W4, Wl, threadIdx.x);
    __syncthreads();
    ACC_ZERO(acc);
    mfma_passS(xx, DD, 0, Wl, rbase, nrows, lane, acc);
    epilogueS<0, 1>(acc, nullptr, nullptr, tb, 256, 128, rbase, nrows, lane);
  } else {
    int nb = gridDim.x - NT;
    int stride = nb * 256;
    for (int j = ((int)blockIdx.x - NT) * 256 + (int)threadIdx.x; j < nnz; j += stride) {
      atomicAdd(&cn[ni[j]], 1);
      atomicAdd(&ce[ei[j]], 1);
    }
  }
}

// fused hidden + GEMM3, 2 row-tiles/block, half in blockIdx.y:
// T = prelu(thb_h@We2n_h + be2n_h); tb_h = bf16(T@Wn2e_h1)
__global__ __launch_bounds__(256, 2) void gemm_fuse_hid_k(const u16* __restrict__ thb,
                                                          const char* W0a, const float* b0a, const char* W1a,
                                                          const char* W0b, const float* b0b, const char* W1b,
                                                          const float* __restrict__ alphap,
                                                          u16* __restrict__ tb_out, int nrows) {
  __shared__ char Wl[65536];
  const int h = blockIdx.y;
  const char* W0 = h ? W0b : W0a;
  const char* W1 = h ? W1b : W1a;
  const float* b0 = h ? b0b : b0a;
  const int wave = threadIdx.x >> 6, lane = threadIdx.x & 63;
  const int r0 = blockIdx.x * 128 + wave * 16;
  const int r1 = r0 + 64;
  const float al = *alphap;
  f4 acc0[8], acc1[8];
  AFragB fT0, fT1;
  stage_w(W0, Wl, threadIdx.x);
  __syncthreads();
  ACC_ZERO(acc0); ACC_ZERO(acc1);
  mfma_passB(thb, 256, h * 128, Wl, r0, nrows, lane, acc0);
  mfma_passB(thb, 256, h * 128, Wl, r1, nrows, lane, acc1);
  __syncthreads();
  acc_to_T(acc0, b0, al, Wl, wave, lane);
  acc_to_T(acc1, b0, al, Wl + 16384, wave, lane);
  __syncthreads();
  load_fT(Wl, wave, lane, fT0);
  load_fT(Wl + 16384, wave, lane, fT1);
  __syncthreads();
  stage_w(W1, Wl, threadIdx.x);
  __syncthreads();
  ACC_ZERO(acc0);
  mfma_pass_fragB(fT0, Wl, lane, acc0);
  epilogueS<0, 1>(acc0, nullptr, nullptr, tb_out, 256, h * 128, r0, nrows, lane);
  ACC_ZERO(acc1);
  mfma_pass_fragB(fT1, Wl, lane, acc1);
  epilogueS<0, 1>(acc1, nullptr, nullptr, tb_out, 256, h * 128, r1, nrows, lane);
}

// encoder final (A = aggb bf16): n1/n2 fp32 + nn1 fp32 + bf16 side copies n1b/n2b
__global__ __launch_bounds__(256, 2) void enc_final_k(const u16* __restrict__ aggb, const char* W1, const float* b1_,
                                                      const char* W2, const float* b2_,
                                                      const float* __restrict__ alphap,
                                                      float* __restrict__ n1, float* __restrict__ n2,
                                                      u16* __restrict__ n1b, u16* __restrict__ n2b,
                                                      float* __restrict__ nn1, int nrows) {
  __shared__ char Wl[65536];
  const int wave = threadIdx.x >> 6, lane = threadIdx.x & 63;
  const int rbase = blockIdx.x * 64 + wave * 16;
  const int cidx = lane & 15;
  f4 acc[8];
  float al = *alphap;
  #pragma unroll 1
  for (int h = 0; h < 2; ++h) {
    if (h) __syncthreads();
    stage_w(h ? W2 : W1, Wl, threadIdx.x);
    __syncthreads();
    const float* bp = h ? b2_ : b1_;
    float* nout = h ? n2 : n1;
    u16* nbout = h ? n2b : n1b;
    float b8[8];
    #pragma unroll
    for (int cb = 0; cb < 8; ++cb) b8[cb] = bp[cb * 16 + cidx];
    ACC_ZERO(acc);
    mfma_passB(aggb, 256, h * 128, Wl, rbase, nrows, lane, acc);
    int rq = rbase + (lane >> 4) * 4;
    #pragma unroll
    for (int q = 0; q < 4; ++q) {
      int row = rq + q;
      if (row < nrows) {
        float* op = nout + (size_t)row * DD + cidx;
        float* op2 = nn1 + (size_t)row * 256 + h * 128 + cidx;
        u16* op3 = nbout + (size_t)row * DD + cidx;
        #pragma unroll
        for (int cb = 0; cb < 8; ++cb) {
          float v = acc[cb][q] + b8[cb];
          v = (v >= 0.f) ? v : al * v;
          op[cb * 16] = v;
          op2[cb * 16] = v;
          op3[cb * 16] = tob(v);
        }
      }
    }
  }
}

// fully-fused decoder: 2 row-tiles/block; y = n-stream, z = d-stream.
// T = prelu(fx@Wx0 + fa@We0 + b0); out = prelu(T@Wx1 + fa@We1 + b1)
__global__ __launch_bounds__(256, 2) void dec_fused_k(const u16* __restrict__ n1b, const u16* __restrict__ n2b,
                                                      const u16* __restrict__ aggb,
                                                      const char* Wx1_0, const char* We1_0, const float* b1_0,
                                                      const char* Wx1_1, const char* We1_1, const float* b1_1,
                                                      const char* Wx2_0, const char* We2_0, const float* b2_0,
                                                      const char* Wx2_1, const char* We2_1, const float* b2_1,
                                                      const float* __restrict__ alphap,
                                                      float* __restrict__ x11, float* __restrict__ x22,
                                                      float* __restrict__ x12, float* __restrict__ x21,
                                                      int nrows) {
  __shared__ char Wl[65536];
  const int y = blockIdx.y, z = blockIdx.z;
  const u16* xb = y ? n2b : n1b;
  float* out = y ? (z ? x21 : x12) : (z ? x22 : x11);
  const char* Wx0 = z ? Wx2_0 : Wx1_0;
  const char* We0 = z ? We2_0 : We1_0;
  const char* Wx1 = z ? Wx2_1 : Wx1_1;
  const char* We1 = z ? We2_1 : We1_1;
  const float* b0 = z ? b2_0 : b1_0;
  const float* b1 = z ? b2_1 : b1_1;
  const int acoff = y * 128;
  const int wave = threadIdx.x >> 6, lane = threadIdx.x & 63;
  const int r0 = blockIdx.x * 128 + wave * 16;
  const int r1 = r0 + 64;
  const float al = *alphap;
  AFragB fx0, fx1, fa0, fa1, fT0, fT1;
  load_afragB(xb, DD, 0, r0, nrows, lane, fx0);
  load_afragB(xb, DD, 0, r1, nrows, lane, fx1);
  load_afragB(aggb, 256, acoff, r0, nrows, lane, fa0);
  load_afragB(aggb, 256, acoff, r1, nrows, lane, fa1);
  f4 acc0[8], acc1[8];
  stage_w(Wx0, Wl, threadIdx.x);
  __syncthreads();
  ACC_ZERO(acc0); ACC_ZERO(acc1);
  mfma_pass_fragB(fx0, Wl, lane, acc0);
  mfma_pass_fragB(fx1, Wl, lane, acc1);
  __syncthreads();
  stage_w(We0, Wl, threadIdx.x);
  __syncthreads();
  mfma_pass_fragB(fa0, Wl, lane, acc0);
  mfma_pass_fragB(fa1, Wl, lane, acc1);
  __syncthreads();
  acc_to_T(acc0, b0, al, Wl, wave, lane);
  acc_to_T(acc1, b0, al, Wl + 16384, wave, lane);
  __syncthreads();
  load_fT(Wl, wave, lane, fT0);
  load_fT(Wl + 16384, wave, lane, fT1);
  __syncthreads();
  stage_w(Wx1, Wl, threadIdx.x);
  __syncthreads();
  ACC_ZERO(acc0); ACC_ZERO(acc1);
  mfma_pass_fragB(fT0, Wl, lane, acc0);
  mfma_pass_fragB(fT1, Wl, lane, acc1);
  __syncthreads();
  stage_w(We1, Wl, threadIdx.x);
  __syncthreads();
  mfma_pass_fragB(fa0, Wl, lane, acc0);
  epilogueS<1, 0>(acc0, b1, alphap, out, DD, 0, r0, nrows, lane);
  mfma_pass_fragB(fa1, Wl, lane, acc1);
  epilogueS<1, 0>(acc1, b1, alphap, out, DD, 0, r1, nrows, lane);
}

// ================= host =================

extern "C" void kernel_launch(void* const* d_in, const int* in_sizes, int n_in,
                              void* d_out, int out_size, void* d_ws, size_t ws_size,
                              hipStream_t stream) {
  const float* x        = (const float*)d_in[0];
  const float* xx       = (const float*)d_in[1];
  const int*   node_idx = (const int*)d_in[2];
  const int*   edge_idx = (const int*)d_in[3];
  const float* alphap   = (const float*)d_in[6];
  const float* e1_Wn2e  = (const float*)d_in[7];
  const float* e1_bn2e  = (const float*)d_in[8];
  const float* e1_We2n  = (const float*)d_in[9];
  const float* e1_be2n  = (const float*)d_in[10];
  const float* e2_Wn2e  = (const float*)d_in[11];
  const float* e2_bn2e  = (const float*)d_in[12];
  const float* e2_We2n  = (const float*)d_in[13];
  const float* e2_be2n  = (const float*)d_in[14];
  const float* d1_We    = (const float*)d_in[15];
  const float* d1_Wx    = (const float*)d_in[16];
  const float* d1_b     = (const float*)d_in[17];
  const float* d2_We    = (const float*)d_in[18];
  const float* d2_Wx    = (const float*)d_in[19];
  const float* d2_b     = (const float*)d_in[20];

  const int N   = in_sizes[0] / DD;
  const int NNZ = in_sizes[2];
  const int E   = (out_size - 1024 * N) / 256;
  const int NBE = (E + 31) >> 5;
  const int NBN = (N + 31) >> 5;
  const int NCHN = (N + 1023) >> 10;
  const int NCHE = (E + 1023) >> 10;

  // ---- d_out slot map ----
  float* out  = (float*)d_out;
  float* nn1  = out;
  float* n1   = out + (size_t)N * 256;
  float* e1o  = n1 + (size_t)N * DD;
  float* n2   = e1o + (size_t)E * DD;
  float* e2o  = n2 + (size_t)N * DD;
  float* x11  = e2o + (size_t)E * DD;
  float* x21  = x11 + (size_t)N * DD;
  float* x12  = x21 + (size_t)N * DD;
  float* x22  = x12 + (size_t)N * DD;

  // ---- workspace carve ----
  size_t off = 0;
  char* w0 = (char*)d_ws;
  auto carve = [&](size_t bytes) -> void* {
    void* p = (void*)(w0 + off);
    off += (bytes + 255) & ~(size_t)255;
    return p;
  };
  int* cn      = (int*)carve((size_t)N * 4);
  int* ce      = (int*)carve((size_t)E * 4);
  int* offs_n  = (int*)carve((size_t)(N + 1) * 4);
  int* offs_e  = (int*)carve((size_t)(E + 1) * 4);
  int* part    = (int*)carve((size_t)(NCHN + NCHE) * 4);
  int* listN   = (int*)carve((size_t)NNZ * 4);
  int* listE   = (int*)carve((size_t)NNZ * 4);
  float* Dn_inv = (float*)carve((size_t)N * 4);
  float* De_inv = (float*)carve((size_t)E * 4);
  char* Wprep  = (char*)carve((size_t)16 * 65536);
  u16* tb      = (u16*)carve((size_t)N * 256 * 2);
  u16* e_fullb = (u16*)carve((size_t)E * 256 * 2);
  u16* thb     = (u16*)carve((size_t)N * 256 * 2);
  u16* aggb    = (u16*)carve((size_t)N * 256 * 2);
  u16* n1b     = (u16*)carve((size_t)N * DD * 2);
  u16* n2b     = (u16*)carve((size_t)N * DD * 2);
  int* cur_be  = (int*)carve((size_t)NBE * 8 * 4);
  int* cur_bn  = (int*)carve((size_t)NBN * 8 * 4);
  u32* SE      = (u32*)carve((size_t)NNZ * 8 * 4);
  u32* SN      = (u32*)carve((size_t)NNZ * 8 * 4);

  // ---- weight prep table ----
  WPtrs wp;
  wp.p[0] = e1_Wn2e;  wp.p[1] = e1_Wn2e + DD * DD;
  wp.p[2] = e1_We2n;  wp.p[3] = e1_We2n + DD * DD;
  wp.p[4] = e2_Wn2e;  wp.p[5] = e2_Wn2e + DD * DD;
  wp.p[6] = e2_We2n;  wp.p[7] = e2_We2n + DD * DD;
  wp.p[8] = d1_We;    wp.p[9] = d1_We + DD * DD;
  wp.p[10] = d1_Wx;   wp.p[11] = d1_Wx + DD * DD;
  wp.p[12] = d2_We;   wp.p[13] = d2_We + DD * DD;
  wp.p[14] = d2_Wx;   wp.p[15] = d2_Wx + DD * DD;
  auto WP = [&](int i) -> const char* { return Wprep + (size_t)i * 65536; };

  const int thr = 256;
  const int gMax = ((N > E ? N : E) + thr - 1) / thr;
  const int NT = (N + 63) / 64;
  const int NT2 = (N + 127) / 128;
  const int HB = 512;
  int gNNZ = (NNZ + thr - 1) / thr; if (gNNZ > 2048) gNNZ = 2048;
  const int gGatE = (E + 3) / 4;
  const int gGatN = (N + 3) / 4;

  prep_w_k<<<128, 256, 0, stream>>>(wp, Wprep);
  init_counts_k<<<gMax, thr, 0, stream>>>(cn, ce, N, E);
  // GEMM1 ∥ histogram
  combo1_k<<<NT + HB, 256, 0, stream>>>(x, WP(0), xx, WP(4), tb, N, NT,
                                        node_idx, edge_idx, cn, ce, NNZ);
  scan_partials_k<<<NCHN + NCHE, 256, 0, stream>>>(cn, ce, part, NCHN, N, NCHE, E);
  scan_apply_k<<<NCHN + NCHE, 256, 0, stream>>>(cn, ce, part, offs_n, offs_e, NCHN, N, NCHE, E);
  fill_deg_k<<<gMax, thr, 0, stream>>>(offs_n, offs_e, Dn_inv, De_inv,
                                       cur_be, cur_bn, N, E, NBE, NBN);
  partition2_k<<<gNNZ, thr, 0, stream>>>(node_idx, edge_idx, cur_be, cur_bn, SE, SN, NNZ);
  scatter_both_k<<<NBE + NBN, 256, 0, stream>>>(SE, offs_e, cur_be, listE, E, NBE,
                                                SN, offs_n, cur_bn, listN, N);

  // ---- fused dual-encoder ----
  gather_edge_k<0><<<gGatE, 256, 0, stream>>>(tb, offs_e, listE, De_inv, e1_bn2e, e2_bn2e,
                                              alphap, e_fullb, nullptr, nullptr, E);
  gather_node_k<<<gGatN, 256, 0, stream>>>(e_fullb, tb, offs_n, listN, Dn_inv, e1_bn2e, e2_bn2e,
                                           alphap, thb, N);
  dim3 gHid(NT2, 2);
  gemm_fuse_hid_k<<<gHid, 256, 0, stream>>>(thb, WP(2), e1_be2n, WP(1),
                                            WP(6), e2_be2n, WP(5), alphap, tb, N);
  gather_edge_k<1><<<gGatE, 256, 0, stream>>>(tb, offs_e, listE, De_inv, e1_bn2e + DD, e2_bn2e + DD,
                                              alphap, e_fullb, e1o, e2o, E);
  gather_node_k<<<gGatN, 256, 0, stream>>>(e_fullb, tb, offs_n, listN, Dn_inv, e1_bn2e + DD, e2_bn2e + DD,
                                           alphap, aggb, N);
  enc_final_k<<<NT, 256, 0, stream>>>(aggb, WP(3), e1_be2n + DD, WP(7), e2_be2n + DD,
                                      alphap, n1, n2, n1b, n2b, nn1, N);

  // ---- fully-fused decoders (2-tile, stream-split grid) ----
  dim3 gDec(NT2, 2, 2);
  dec_fused_k<<<gDec, 256, 0, stream>>>(n1b, n2b, aggb,
                                        WP(10), WP(8), d1_b, WP(11), WP(9), d1_b + DD,
                                        WP(14), WP(12), d2_b, WP(15), WP(13), d2_b + DD,
                                        alphap, x11, x22, x12, x21, N);
}

// Round 13
// 585.282 us; speedup vs baseline: 1.2180x; 1.2180x over previous
//
#include <hip/hip_runtime.h>

#define DD 128

typedef __attribute__((ext_vector_type(8))) short bh8;       // 8 bf16 (as i16 bits)
typedef __attribute__((ext_vector_type(8))) unsigned short us8;
typedef __attribute__((ext_vector_type(4))) float f4;
typedef unsigned int u32;
typedef unsigned short u16;

__device__ __forceinline__ u16 tob(float f) {           // fp32 -> bf16 RNE
  u32 u = __builtin_bit_cast(u32, f);
  u += 0x7FFFu + ((u >> 16) & 1u);
  return (u16)(u >> 16);
}
__device__ __forceinline__ float fb(u16 h) { return __builtin_bit_cast(float, (u32)h << 16); }

// ================= CSR build (real edges only; self-loops analytic) =================

__global__ __launch_bounds__(256) void init_counts_k(int* cn, int* ce, int N, int E) {
  int g = blockIdx.x * blockDim.x + threadIdx.x;
  if (g < E) ce[g] = 0;
  if (g < N) cn[g] = 0;
}

// ---- parallel hierarchical exclusive scan (chunks of 1024) ----

__global__ __launch_bounds__(256) void scan_partials_k(const int* __restrict__ cn, const int* __restrict__ ce,
                                                       int* part, int NCHN, int N, int NCHE, int E) {
  __shared__ int red[256];
  int b = blockIdx.x, tid = threadIdx.x;
  const int* cnt = (b < NCHN) ? cn : ce;
  int n = (b < NCHN) ? N : E;
  int base = ((b < NCHN) ? b : (b - NCHN)) << 10;
  int i0 = base + tid * 4;
  int s = 0;
  #pragma unroll
  for (int j = 0; j < 4; ++j) { int i = i0 + j; if (i < n) s += cnt[i]; }
  red[tid] = s; __syncthreads();
  for (int off = 128; off > 0; off >>= 1) {
    if (tid < off) red[tid] += red[tid + off];
    __syncthreads();
  }
  if (tid == 0) part[b] = red[0];
}

__device__ __forceinline__ int blk_excl_scan(int s, int tid, int* sums) {
  sums[tid] = s; __syncthreads();
  for (int off = 1; off < 256; off <<= 1) {
    int t = (tid >= off) ? sums[tid - off] : 0;
    __syncthreads();
    sums[tid] += t;
    __syncthreads();
  }
  int ex = sums[tid] - s;
  __syncthreads();
  return ex;
}

// scan_apply with inlined chunk-prefix (part[] holds RAW chunk sums)
__global__ __launch_bounds__(256) void scan_apply_k(const int* __restrict__ cn, const int* __restrict__ ce,
                                                    const int* __restrict__ part,
                                                    int* offs_n, int* offs_e,
                                                    int NCHN, int N, int NCHE, int E) {
  __shared__ int sums[256];
  __shared__ int base_s;
  int b = blockIdx.x, tid = threadIdx.x;
  const bool isN = b < NCHN;
  const int* cnt = isN ? cn : ce;
  int* offs = isN ? offs_n : offs_e;
  int n = isN ? N : E;
  int nch = isN ? NCHN : NCHE;
  int c = isN ? b : b - NCHN;
  const int* pbase = isN ? part : part + NCHN;
  {
    int v = (tid < nch) ? pbase[tid] : 0;
    int ex = blk_excl_scan(v, tid, sums);
    if (tid == c) base_s = ex;
  }
  __syncthreads();
  int base = (c << 10);
  int i0 = base + tid * 4;
  int v[4]; int s = 0;
  #pragma unroll
  for (int j = 0; j < 4; ++j) { int i = i0 + j; int t = (i < n) ? cnt[i] : 0; v[j] = t; s += t; }
  int ex = blk_excl_scan(s, tid, sums);
  int run = base_s + ex;
  #pragma unroll
  for (int j = 0; j < 4; ++j) { int i = i0 + j; if (i < n) offs[i] = run; run += v[j]; }
  if (tid == 255 && base + 1024 >= n) offs[n] = run;
}

__global__ __launch_bounds__(256) void fill_deg_k(const int* __restrict__ offs_n, const int* __restrict__ offs_e,
                                                  float* Dn_inv, float* De_inv,
                                                  int* cur_be, int* cur_bn,
                                                  int N, int E, int NBE, int NBN) {
  int g = blockIdx.x * blockDim.x + threadIdx.x;
  if (g < E) {
    int b = offs_e[g], e = offs_e[g + 1];
    De_inv[g] = (e > b) ? 1.0f / (float)(e - b) : 0.0f;
  }
  if (g < N) {
    int b = offs_n[g], e = offs_n[g + 1];
    Dn_inv[g] = 1.0f / (float)(e - b + 1);   // +1 self loop
  }
  if (g < NBE) {
    int r1 = (g + 1) * 32; if (r1 > E) r1 = E;
    int o0 = offs_e[g * 32], o1 = offs_e[r1];
    int C = o1 - o0, base = 8 * o0;
    #pragma unroll
    for (int k = 0; k < 8; ++k) cur_be[g * 8 + k] = base + k * C;
  }
  if (g < NBN) {
    int r1 = (g + 1) * 32; if (r1 > N) r1 = N;
    int o0 = offs_n[g * 32], o1 = offs_n[r1];
    int C = o1 - o0, base = 8 * o0;
    #pragma unroll
    for (int k = 0; k < 8; ++k) cur_bn[g * 8 + k] = base + k * C;
  }
}

__global__ __launch_bounds__(256) void partition2_k(const int* __restrict__ ni, const int* __restrict__ ei,
                                                    int* cur_be, int* cur_bn,
                                                    u32* __restrict__ SE, u32* __restrict__ SN, int nnz) {
  int xcd;
  asm volatile("s_getreg_b32 %0, hwreg(HW_REG_XCC_ID)" : "=s"(xcd));
  xcd &= 7;
  int stride = gridDim.x * blockDim.x;
  for (int j = blockIdx.x * blockDim.x + threadIdx.x; j < nnz; j += stride) {
    int n = ni[j], e = ei[j];
    int pe = atomicAdd(&cur_be[(e >> 5) * 8 + xcd], 1);
    SE[pe] = ((u32)(e & 31) << 17) | (u32)n;
    int pn = atomicAdd(&cur_bn[(n >> 5) * 8 + xcd], 1);
    SN[pn] = ((u32)(n & 31) << 17) | (u32)e;
  }
}

__device__ __forceinline__ void scatter_body(const u32* __restrict__ S, const int* __restrict__ offs,
                                             const int* __restrict__ cur_b,
                                             int* __restrict__ list, int nRows, int b, int tid, int* cur) {
  const int i0 = b << 5;
  if (tid < 32) {
    int row = i0 + tid;
    cur[tid] = (row < nRows) ? offs[row] : 0;
  }
  __syncthreads();
  int r1 = i0 + 32; if (r1 > nRows) r1 = nRows;
  const int o0 = offs[i0];
  const int C = offs[r1] - o0;
  #pragma unroll 1
  for (int k = 0; k < 8; ++k) {
    int sbeg = 8 * o0 + k * C;
    int send = cur_b[b * 8 + k];
    for (int i = sbeg + tid; i < send; i += 256) {
      u32 v = S[i];
      int pos = atomicAdd(&cur[v >> 17], 1);
      list[pos] = (int)(v & 0x1FFFFu);
    }
  }
}

__global__ __launch_bounds__(256) void scatter_both_k(const u32* SE, const int* offs_e, const int* cur_be,
                                                      int* listE, int E, int NBE,
                                                      const u32* SN, const int* offs_n, const int* cur_bn,
                                                      int* listN, int N) {
  __shared__ int cur[32];
  int b = blockIdx.x, tid = threadIdx.x;
  if (b < NBE) scatter_body(SE, offs_e, cur_be, listE, E, b, tid, cur);
  else         scatter_body(SN, offs_n, cur_bn, listN, N, b - NBE, tid, cur);
}

// ================= gathers (width 256, bf16, split-wave: 16B/lane) =================

__device__ __forceinline__ void acc8(float a[8], us8 v) {
  #pragma unroll
  for (int j = 0; j < 8; ++j) a[j] += fb(v[j]);
}

template<int SPLIT>
__global__ __launch_bounds__(256) void gather_edge_k(const u16* __restrict__ srcb,
                                                     const int* __restrict__ offs, const int* __restrict__ list,
                                                     const float* __restrict__ De_inv,
                                                     const float* __restrict__ b1, const float* __restrict__ b2,
                                                     const float* __restrict__ alphap,
                                                     u16* __restrict__ e_fullb,
                                                     float* __restrict__ d2a, float* __restrict__ d2b, int E) {
  const int wave = threadIdx.x >> 6, lane = threadIdx.x & 63;
  const int row = blockIdx.x * 4 + wave;
  if (row >= E) return;
  const int half = lane >> 5, cl = lane & 31;
  const int c8 = cl * 8;
  const int beg = offs[row], end = offs[row + 1];
  float a0[8] = {0,0,0,0,0,0,0,0}, a1[8] = {0,0,0,0,0,0,0,0};
  int i = beg + half;
  for (; i + 2 < end; i += 4) {
    us8 v0 = *(const us8*)&srcb[(size_t)list[i] * 256 + c8];
    us8 v1 = *(const us8*)&srcb[(size_t)list[i + 2] * 256 + c8];
    acc8(a0, v0); acc8(a1, v1);
  }
  if (i < end) acc8(a0, *(const us8*)&srcb[(size_t)list[i] * 256 + c8]);
  float s[8];
  #pragma unroll
  for (int j = 0; j < 8; ++j) s[j] = a0[j] + a1[j];
  #pragma unroll
  for (int j = 0; j < 8; ++j) s[j] += __shfl_xor(s[j], 32);
  if (half == 0) {
    float sc = De_inv[row];
    const float* bp = (c8 < 128) ? (b1 + c8) : (b2 + c8 - 128);
    float4 bt0 = *(const float4*)bp;
    float4 bt1 = *(const float4*)(bp + 4);
    float bb[8] = {bt0.x, bt0.y, bt0.z, bt0.w, bt1.x, bt1.y, bt1.z, bt1.w};
    float al = *alphap;
    us8 ob;
    float ov[8];
    #pragma unroll
    for (int j = 0; j < 8; ++j) {
      float v = sc * s[j] + bb[j];
      v = (v >= 0.f) ? v : al * v;
      ov[j] = v; ob[j] = tob(v);
    }
    *(us8*)&e_fullb[(size_t)row * 256 + c8] = ob;
    if constexpr (SPLIT == 1) {
      float* dp = (c8 < 128) ? &d2a[(size_t)row * DD + c8] : &d2b[(size_t)row * DD + c8 - 128];
      float4 w0 = {ov[0], ov[1], ov[2], ov[3]};
      float4 w1 = {ov[4], ov[5], ov[6], ov[7]};
      *(float4*)dp = w0;
      *(float4*)(dp + 4) = w1;
    }
  }
}

__global__ __launch_bounds__(256) void gather_node_k(const u16* __restrict__ e_fullb,
                                                     const u16* __restrict__ tb,
                                                     const int* __restrict__ offs, const int* __restrict__ list,
                                                     const float* __restrict__ Dn_inv,
                                                     const float* __restrict__ b1, const float* __restrict__ b2,
                                                     const float* __restrict__ alphap,
                                                     u16* __restrict__ dstb, int N) {
  const int wave = threadIdx.x >> 6, lane = threadIdx.x & 63;
  const int row = blockIdx.x * 4 + wave;
  if (row >= N) return;
  const int half = lane >> 5, cl = lane & 31;
  const int c8 = cl * 8;
  const int beg = offs[row], end = offs[row + 1];
  float a0[8] = {0,0,0,0,0,0,0,0}, a1[8] = {0,0,0,0,0,0,0,0};
  int i = beg + half;
  for (; i + 2 < end; i += 4) {
    us8 v0 = *(const us8*)&e_fullb[(size_t)list[i] * 256 + c8];
    us8 v1 = *(const us8*)&e_fullb[(size_t)list[i + 2] * 256 + c8];
    acc8(a0, v0); acc8(a1, v1);
  }
  if (i < end) acc8(a0, *(const us8*)&e_fullb[(size_t)list[i] * 256 + c8]);
  float s[8];
  #pragma unroll
  for (int j = 0; j < 8; ++j) s[j] = a0[j] + a1[j];
  #pragma unroll
  for (int j = 0; j < 8; ++j) s[j] += __shfl_xor(s[j], 32);
  if (half == 0) {
    us8 tv = *(const us8*)&tb[(size_t)row * 256 + c8];
    const float* bp = (c8 < 128) ? (b1 + c8) : (b2 + c8 - 128);
    float4 bt0 = *(const float4*)bp;
    float4 bt1 = *(const float4*)(bp + 4);
    float bb[8] = {bt0.x, bt0.y, bt0.z, bt0.w, bt1.x, bt1.y, bt1.z, bt1.w};
    float al = *alphap;
    float sc = Dn_inv[row];
    us8 ob;
    #pragma unroll
    for (int j = 0; j < 8; ++j) {
      float sv = fb(tv[j]) + bb[j];
      sv = (sv >= 0.f) ? sv : al * sv;
      ob[j] = tob(sc * (sv + s[j]));
    }
    *(us8*)&dstb[(size_t)row * 256 + c8] = ob;
  }
}

// ================= weight prep =================

struct WPtrs { const float* p[16]; };

__global__ __launch_bounds__(256) void prep_w_k(WPtrs wp, char* dst) {
  int m = blockIdx.x >> 3, s = blockIdx.x & 7;
  const float* W = wp.p[m];
  int t = threadIdx.x;
  int n = t & 127;
  int k0 = s * 16 + (t >> 7) * 8;
  us8 vhi, vlo;
  #pragma unroll
  for (int j = 0; j < 8; ++j) {
    float x = W[(size_t)(k0 + j) * DD + n];
    u32 ux = __builtin_bit_cast(u32, x);
    float hf = __builtin_bit_cast(float, ux & 0xFFFF0000u);
    float l = x - hf;
    vhi[j] = (u16)(ux >> 16);
    vlo[j] = (u16)(__builtin_bit_cast(u32, l) >> 16);
  }
  char* base = dst + (size_t)m * 65536;
  int byte = n * 256 + k0 * 2;
  byte ^= (n & 7) << 4;
  *(us8*)(base + byte) = vhi;
  *(us8*)(base + 32768 + byte) = vlo;
}

// ================= MFMA machinery =================

__device__ __forceinline__ void stage_w(const char* gsrc, char* lds, int tid) {
  int wave = tid >> 6, lane = tid & 63;
  #pragma unroll
  for (int i = 0; i < 16; ++i) {
    int off = (wave * 16 + i) * 1024;
    __builtin_amdgcn_global_load_lds(
        (const __attribute__((address_space(1))) u32*)(gsrc + off + lane * 16),
        (__attribute__((address_space(3))) u32*)(lds + off), 16, 0, 0);
  }
}

__device__ __forceinline__ void split8(const float vs[8], bh8& hi, bh8& lo) {
  #pragma unroll
  for (int j = 0; j < 8; ++j) {
    u32 u = __builtin_bit_cast(u32, vs[j]);
    float hf = __builtin_bit_cast(float, u & 0xFFFF0000u);
    float l = vs[j] - hf;
    hi[j] = (short)(u >> 16);
    lo[j] = (short)(__builtin_bit_cast(u32, l) >> 16);
  }
}

__device__ __forceinline__ void mk_afrag(const float* rowp, int koff, bh8& hi, bh8& lo) {
  float4 v0 = *(const float4*)(rowp + koff);
  float4 v1 = *(const float4*)(rowp + koff + 4);
  float vs[8] = {v0.x, v0.y, v0.z, v0.w, v1.x, v1.y, v1.z, v1.w};
  split8(vs, hi, lo);
}

// fp32-A split-3 path
__device__ __forceinline__ void mfma_ks(const bh8& ahi, const bh8& alo, const char* Wl,
                                        int ks, int lane, f4 acc[8]) {
  const int koff0 = (lane >> 4) * 8;
  const int k2 = (ks * 32 + koff0) * 2;
  #pragma unroll
  for (int cb = 0; cb < 8; ++cb) {
    int n = cb * 16 + (lane & 15);
    int byte = (n * 256 + k2) ^ ((n & 7) << 4);
    bh8 bhiF = *(const bh8*)(Wl + byte);
    bh8 bloF = *(const bh8*)(Wl + 32768 + byte);
    acc[cb] = __builtin_amdgcn_mfma_f32_16x16x32_bf16(ahi, bhiF, acc[cb], 0, 0, 0);
    acc[cb] = __builtin_amdgcn_mfma_f32_16x16x32_bf16(ahi, bloF, acc[cb], 0, 0, 0);
    acc[cb] = __builtin_amdgcn_mfma_f32_16x16x32_bf16(alo, bhiF, acc[cb], 0, 0, 0);
  }
}

// bf16-A exact path (2 MFMA)
__device__ __forceinline__ void mfma_ks_bf(const bh8& a, const char* Wl,
                                           int ks, int lane, f4 acc[8]) {
  const int koff0 = (lane >> 4) * 8;
  const int k2 = (ks * 32 + koff0) * 2;
  #pragma unroll
  for (int cb = 0; cb < 8; ++cb) {
    int n = cb * 16 + (lane & 15);
    int byte = (n * 256 + k2) ^ ((n & 7) << 4);
    bh8 bhiF = *(const bh8*)(Wl + byte);
    bh8 bloF = *(const bh8*)(Wl + 32768 + byte);
    acc[cb] = __builtin_amdgcn_mfma_f32_16x16x32_bf16(a, bhiF, acc[cb], 0, 0, 0);
    acc[cb] = __builtin_amdgcn_mfma_f32_16x16x32_bf16(a, bloF, acc[cb], 0, 0, 0);
  }
}

__device__ __forceinline__ void mfma_passS(const float* __restrict__ A, size_t astride, int acoff,
                                           const char* Wl, int rbase, int nrows, int lane, f4 acc[8]) {
  int r = rbase + (lane & 15);
  if (r >= nrows) r = nrows - 1;
  const float* rowp = A + (size_t)r * astride + acoff;
  const int koff0 = (lane >> 4) * 8;
  #pragma unroll
  for (int ks = 0; ks < 4; ++ks) {
    bh8 ahi, alo;
    mk_afrag(rowp, ks * 32 + koff0, ahi, alo);
    mfma_ks(ahi, alo, Wl, ks, lane, acc);
  }
}

__device__ __forceinline__ void mfma_passB(const u16* __restrict__ A, size_t astride, int acoff,
                                           const char* Wl, int rbase, int nrows, int lane, f4 acc[8]) {
  int r = rbase + (lane & 15);
  if (r >= nrows) r = nrows - 1;
  const u16* rowp = A + (size_t)r * astride + acoff;
  const int koff0 = (lane >> 4) * 8;
  #pragma unroll
  for (int ks = 0; ks < 4; ++ks) {
    bh8 a = __builtin_bit_cast(bh8, *(const us8*)(rowp + ks * 32 + koff0));
    mfma_ks_bf(a, Wl, ks, lane, acc);
  }
}

struct AFragB { bh8 a[4]; };

__device__ __forceinline__ void load_afragB(const u16* __restrict__ A, size_t astride, int acoff,
                                            int rbase, int nrows, int lane, AFragB& f) {
  int r = rbase + (lane & 15);
  if (r >= nrows) r = nrows - 1;
  const u16* rowp = A + (size_t)r * astride + acoff;
  const int koff0 = (lane >> 4) * 8;
  #pragma unroll
  for (int ks = 0; ks < 4; ++ks)
    f.a[ks] = __builtin_bit_cast(bh8, *(const us8*)(rowp + ks * 32 + koff0));
}

__device__ __forceinline__ void mfma_pass_fragB(const AFragB& f, const char* Wl, int lane, f4 acc[8]) {
  #pragma unroll
  for (int ks = 0; ks < 4; ++ks) mfma_ks_bf(f.a[ks], Wl, ks, lane, acc);
}

// ---- LDS T-tile (64 rows x 128 bf16, XOR-swizzled, aliased into Wl[0:16KB]) ----

__device__ __forceinline__ void acc_to_T(f4 acc[8], const float* bias, float al,
                                         char* Tb, int wave, int lane) {
  const int cidx = lane & 15;
  float b8[8];
  #pragma unroll
  for (int cb = 0; cb < 8; ++cb) b8[cb] = bias[cb * 16 + cidx];
  #pragma unroll
  for (int q = 0; q < 4; ++q) {
    int row = wave * 16 + (lane >> 4) * 4 + q;
    #pragma unroll
    for (int cb = 0; cb < 8; ++cb) {
      float v = acc[cb][q] + b8[cb];
      v = (v >= 0.f) ? v : al * v;
      int byte = (row * 256 + (cb * 16 + cidx) * 2) ^ ((row & 7) << 4);
      *(u16*)(Tb + byte) = tob(v);
    }
  }
}

__device__ __forceinline__ void load_fT(const char* Tb, int wave, int lane, AFragB& f) {
  const int row = wave * 16 + (lane & 15);
  const int koff0 = (lane >> 4) * 8;
  #pragma unroll
  for (int ks = 0; ks < 4; ++ks) {
    int byte = (row * 256 + (ks * 32 + koff0) * 2) ^ ((row & 7) << 4);
    f.a[ks] = __builtin_bit_cast(bh8, *(const us8*)(Tb + byte));
  }
}

// MODE 0: raw; MODE 1: +bias +prelu.  OBF: write bf16 instead of fp32.
template<int MODE, int OBF>
__device__ __forceinline__ void epilogueS(f4 acc[8], const float* bias, const float* alphap,
                                          void* outp, size_t ostride, int ocoff,
                                          int rbase, int nrows, int lane) {
  float al = 0.f;
  if constexpr (MODE == 1) al = *alphap;
  const int cidx = lane & 15;
  int rq = rbase + (lane >> 4) * 4;
  float b8[8];
  if constexpr (MODE == 1) {
    #pragma unroll
    for (int cb = 0; cb < 8; ++cb) b8[cb] = bias[cb * 16 + cidx];
  }
  #pragma unroll
  for (int q = 0; q < 4; ++q) {
    int row = rq + q;
    if (row < nrows) {
      #pragma unroll
      for (int cb = 0; cb < 8; ++cb) {
        float v = acc[cb][q];
        if constexpr (MODE == 1) { v += b8[cb]; v = (v >= 0.f) ? v : al * v; }
        if constexpr (OBF == 1) {
          u16* op = (u16*)outp + (size_t)row * ostride + ocoff + cidx;
          op[cb * 16] = tob(v);
        } else {
          float* op = (float*)outp + (size_t)row * ostride + ocoff + cidx;
          op[cb * 16] = v;
        }
      }
    }
  }
}

#define ACC_ZERO(acc) { _Pragma("unroll") for (int cb = 0; cb < 8; ++cb) acc[cb] = {0.f, 0.f, 0.f, 0.f}; }

// ================= GEMM kernels (per-tile grids, single 64-row tile) =================

// combo: blocks [0,NT) = GEMM1; blocks [NT, NT+HB) = histogram (grid-stride)
__global__ __launch_bounds__(256, 2) void combo1_k(const float* __restrict__ x, const char* W0,
                                                   const float* __restrict__ xx, const char* W4,
                                                   u16* __restrict__ tb, int nrows, int NT,
                                                   const int* __restrict__ ni, const int* __restrict__ ei,
                                                   int* cn, int* ce, int nnz) {
  __shared__ char Wl[65536];
  if ((int)blockIdx.x < NT) {
    const int wave = threadIdx.x >> 6, lane = threadIdx.x & 63;
    const int rbase = blockIdx.x * 64 + wave * 16;
    f4 acc[8];
    stage_w(W0, Wl, threadIdx.x);
    __syncthreads();
    ACC_ZERO(acc);
    mfma_passS(x, DD, 0, Wl, rbase, nrows, lane, acc);
    epilogueS<0, 1>(acc, nullptr, nullptr, tb, 256, 0, rbase, nrows, lane);
    __syncthreads();
    stage_w(W4, Wl, threadIdx.x);
    __syncthreads();
    ACC_ZERO(acc);
    mfma_passS(xx, DD, 0, Wl, rbase, nrows, lane, acc);
    epilogueS<0, 1>(acc, nullptr, nullptr, tb, 256, 128, rbase, nrows, lane);
  } else {
    int nb = gridDim.x - NT;
    int stride = nb * 256;
    for (int j = ((int)blockIdx.x - NT) * 256 + (int)threadIdx.x; j < nnz; j += stride) {
      atomicAdd(&cn[ni[j]], 1);
      atomicAdd(&ce[ei[j]], 1);
    }
  }
}

// fused hidden + GEMM3 per half (round-11 proven shape):
// T = prelu(thb_h@We2n_h + be2n_h); tb_h = bf16(T@Wn2e_h1)
__global__ __launch_bounds__(256, 2) void gemm_fuse_hid_k(const u16* __restrict__ thb,
                                                          const char* W20, const float* b20, const char* W21,
                                                          const char* W60, const float* b60, const char* W61,
                                                          const float* __restrict__ alphap,
                                                          u16* __restrict__ tb_out, int nrows) {
  __shared__ char Wl[65536];
  const int wave = threadIdx.x >> 6, lane = threadIdx.x & 63;
  const int rbase = blockIdx.x * 64 + wave * 16;
  const float al = *alphap;
  f4 acc[8];
  AFragB fT;
  #pragma unroll 1
  for (int h = 0; h < 2; ++h) {
    if (h) __syncthreads();
    stage_w(h ? W60 : W20, Wl, threadIdx.x);
    __syncthreads();
    ACC_ZERO(acc);
    mfma_passB(thb, 256, h * 128, Wl, rbase, nrows, lane, acc);
    __syncthreads();
    acc_to_T(acc, h ? b60 : b20, al, Wl, wave, lane);
    __syncthreads();
    load_fT(Wl, wave, lane, fT);
    __syncthreads();
    stage_w(h ? W61 : W21, Wl, threadIdx.x);
    __syncthreads();
    ACC_ZERO(acc);
    mfma_pass_fragB(fT, Wl, lane, acc);
    epilogueS<0, 1>(acc, nullptr, nullptr, tb_out, 256, h * 128, rbase, nrows, lane);
  }
}

// encoder final (A = aggb bf16): n1/n2 fp32 + nn1 fp32 + bf16 side copies n1b/n2b
__global__ __launch_bounds__(256, 2) void enc_final_k(const u16* __restrict__ aggb, const char* W1, const float* b1_,
                                                      const char* W2, const float* b2_,
                                                      const float* __restrict__ alphap,
                                                      float* __restrict__ n1, float* __restrict__ n2,
                                                      u16* __restrict__ n1b, u16* __restrict__ n2b,
                                                      float* __restrict__ nn1, int nrows) {
  __shared__ char Wl[65536];
  const int wave = threadIdx.x >> 6, lane = threadIdx.x & 63;
  const int rbase = blockIdx.x * 64 + wave * 16;
  const int cidx = lane & 15;
  f4 acc[8];
  float al = *alphap;
  #pragma unroll 1
  for (int h = 0; h < 2; ++h) {
    if (h) __syncthreads();
    stage_w(h ? W2 : W1, Wl, threadIdx.x);
    __syncthreads();
    const float* bp = h ? b2_ : b1_;
    float* nout = h ? n2 : n1;
    u16* nbout = h ? n2b : n1b;
    float b8[8];
    #pragma unroll
    for (int cb = 0; cb < 8; ++cb) b8[cb] = bp[cb * 16 + cidx];
    ACC_ZERO(acc);
    mfma_passB(aggb, 256, h * 128, Wl, rbase, nrows, lane, acc);
    int rq = rbase + (lane >> 4) * 4;
    #pragma unroll
    for (int q = 0; q < 4; ++q) {
      int row = rq + q;
      if (row < nrows) {
        float* op = nout + (size_t)row * DD + cidx;
        float* op2 = nn1 + (size_t)row * 256 + h * 128 + cidx;
        u16* op3 = nbout + (size_t)row * DD + cidx;
        #pragma unroll
        for (int cb = 0; cb < 8; ++cb) {
          float v = acc[cb][q] + b8[cb];
          v = (v >= 0.f) ? v : al * v;
          op[cb * 16] = v;
          op2[cb * 16] = v;
          op3[cb * 16] = tob(v);
        }
      }
    }
  }
}

// fully-fused decoder (round-11 proven shape): 1 tile, y = n-stream, serial d-stream loop.
__global__ __launch_bounds__(256, 2) void dec_fused_k(const u16* __restrict__ n1b, const u16* __restrict__ n2b,
                                                      const u16* __restrict__ aggb,
                                                      const char* Wx10, const char* We10, const float* b1_0,
                                                      const char* Wx11, const char* We11, const float* b1_1,
                                                      const char* Wx20, const char* We20, const float* b2_0,
                                                      const char* Wx21, const char* We21, const float* b2_1,
                                                      const float* __restrict__ alphap,
                                                      float* __restrict__ x11, float* __restrict__ x22,
                                                      float* __restrict__ x12, float* __restrict__ x21,
                                                      int nrows) {
  __shared__ char Wl[65536];
  const int y = blockIdx.y;
  const u16* xb = y ? n2b : n1b;
  float* od1 = y ? x12 : x11;
  float* od2 = y ? x21 : x22;
  const int acoff = y * 128;
  const int wave = threadIdx.x >> 6, lane = threadIdx.x & 63;
  const int rbase = blockIdx.x * 64 + wave * 16;
  const float al = *alphap;
  AFragB fx, fa, fT;
  load_afragB(xb, DD, 0, rbase, nrows, lane, fx);
  load_afragB(aggb, 256, acoff, rbase, nrows, lane, fa);
  f4 acc[8];
  #pragma unroll 1
  for (int s = 0; s < 2; ++s) {
    const char* Wx0 = s ? Wx20 : Wx10;
    const char* We0 = s ? We20 : We10;
    const char* Wx1 = s ? Wx21 : Wx11;
    const char* We1 = s ? We21 : We11;
    const float* b0 = s ? b2_0 : b1_0;
    const float* b1 = s ? b2_1 : b1_1;
    float* out = s ? od2 : od1;
    if (s) __syncthreads();
    stage_w(Wx0, Wl, threadIdx.x);
    __syncthreads();
    ACC_ZERO(acc);
    mfma_pass_fragB(fx, Wl, lane, acc);
    __syncthreads();
    stage_w(We0, Wl, threadIdx.x);
    __syncthreads();
    mfma_pass_fragB(fa, Wl, lane, acc);
    __syncthreads();
    acc_to_T(acc, b0, al, Wl, wave, lane);
    __syncthreads();
    load_fT(Wl, wave, lane, fT);
    __syncthreads();
    stage_w(Wx1, Wl, threadIdx.x);
    __syncthreads();
    ACC_ZERO(acc);
    mfma_pass_fragB(fT, Wl, lane, acc);
    __syncthreads();
    stage_w(We1, Wl, threadIdx.x);
    __syncthreads();
    mfma_pass_fragB(fa, Wl, lane, acc);
    epilogueS<1, 0>(acc, b1, alphap, out, DD, 0, rbase, nrows, lane);
  }
}

// ================= host =================

extern "C" void kernel_launch(void* const* d_in, const int* in_sizes, int n_in,
                              void* d_out, int out_size, void* d_ws, size_t ws_size,
                              hipStream_t stream) {
  const float* x        = (const float*)d_in[0];
  const float* xx       = (const float*)d_in[1];
  const int*   node_idx = (const int*)d_in[2];
  const int*   edge_idx = (const int*)d_in[3];
  const float* alphap   = (const float*)d_in[6];
  const float* e1_Wn2e  = (const float*)d_in[7];
  const float* e1_bn2e  = (const float*)d_in[8];
  const float* e1_We2n  = (const float*)d_in[9];
  const float* e1_be2n  = (const float*)d_in[10];
  const float* e2_Wn2e  = (const float*)d_in[11];
  const float* e2_bn2e  = (const float*)d_in[12];
  const float* e2_We2n  = (const float*)d_in[13];
  const float* e2_be2n  = (const float*)d_in[14];
  const float* d1_We    = (const float*)d_in[15];
  const float* d1_Wx    = (const float*)d_in[16];
  const float* d1_b     = (const float*)d_in[17];
  const float* d2_We    = (const float*)d_in[18];
  const float* d2_Wx    = (const float*)d_in[19];
  const float* d2_b     = (const float*)d_in[20];

  const int N   = in_sizes[0] / DD;
  const int NNZ = in_sizes[2];
  const int E   = (out_size - 1024 * N) / 256;
  const int NBE = (E + 31) >> 5;
  const int NBN = (N + 31) >> 5;
  const int NCHN = (N + 1023) >> 10;
  const int NCHE = (E + 1023) >> 10;

  // ---- d_out slot map ----
  float* out  = (float*)d_out;
  float* nn1  = out;
  float* n1   = out + (size_t)N * 256;
  float* e1o  = n1 + (size_t)N * DD;
  float* n2   = e1o + (size_t)E * DD;
  float* e2o  = n2 + (size_t)N * DD;
  float* x11  = e2o + (size_t)E * DD;
  float* x21  = x11 + (size_t)N * DD;
  float* x12  = x21 + (size_t)N * DD;
  float* x22  = x12 + (size_t)N * DD;

  // ---- workspace carve ----
  size_t off = 0;
  char* w0 = (char*)d_ws;
  auto carve = [&](size_t bytes) -> void* {
    void* p = (void*)(w0 + off);
    off += (bytes + 255) & ~(size_t)255;
    return p;
  };
  int* cn      = (int*)carve((size_t)N * 4);
  int* ce      = (int*)carve((size_t)E * 4);
  int* offs_n  = (int*)carve((size_t)(N + 1) * 4);
  int* offs_e  = (int*)carve((size_t)(E + 1) * 4);
  int* part    = (int*)carve((size_t)(NCHN + NCHE) * 4);
  int* listN   = (int*)carve((size_t)NNZ * 4);
  int* listE   = (int*)carve((size_t)NNZ * 4);
  float* Dn_inv = (float*)carve((size_t)N * 4);
  float* De_inv = (float*)carve((size_t)E * 4);
  char* Wprep  = (char*)carve((size_t)16 * 65536);
  u16* tb      = (u16*)carve((size_t)N * 256 * 2);
  u16* e_fullb = (u16*)carve((size_t)E * 256 * 2);
  u16* thb     = (u16*)carve((size_t)N * 256 * 2);
  u16* aggb    = (u16*)carve((size_t)N * 256 * 2);
  u16* n1b     = (u16*)carve((size_t)N * DD * 2);
  u16* n2b     = (u16*)carve((size_t)N * DD * 2);
  int* cur_be  = (int*)carve((size_t)NBE * 8 * 4);
  int* cur_bn  = (int*)carve((size_t)NBN * 8 * 4);
  u32* SE      = (u32*)carve((size_t)NNZ * 8 * 4);
  u32* SN      = (u32*)carve((size_t)NNZ * 8 * 4);

  // ---- weight prep table ----
  WPtrs wp;
  wp.p[0] = e1_Wn2e;  wp.p[1] = e1_Wn2e + DD * DD;
  wp.p[2] = e1_We2n;  wp.p[3] = e1_We2n + DD * DD;
  wp.p[4] = e2_Wn2e;  wp.p[5] = e2_Wn2e + DD * DD;
  wp.p[6] = e2_We2n;  wp.p[7] = e2_We2n + DD * DD;
  wp.p[8] = d1_We;    wp.p[9] = d1_We + DD * DD;
  wp.p[10] = d1_Wx;   wp.p[11] = d1_Wx + DD * DD;
  wp.p[12] = d2_We;   wp.p[13] = d2_We + DD * DD;
  wp.p[14] = d2_Wx;   wp.p[15] = d2_Wx + DD * DD;
  auto WP = [&](int i) -> const char* { return Wprep + (size_t)i * 65536; };

  const int thr = 256;
  const int gMax = ((N > E ? N : E) + thr - 1) / thr;
  const int NT = (N + 63) / 64;
  const int HB = 512;
  int gNNZ = (NNZ + thr - 1) / thr; if (gNNZ > 2048) gNNZ = 2048;
  const int gGatE = (E + 3) / 4;
  const int gGatN = (N + 3) / 4;

  prep_w_k<<<128, 256, 0, stream>>>(wp, Wprep);
  init_counts_k<<<gMax, thr, 0, stream>>>(cn, ce, N, E);
  // GEMM1 ∥ histogram
  combo1_k<<<NT + HB, 256, 0, stream>>>(x, WP(0), xx, WP(4), tb, N, NT,
                                        node_idx, edge_idx, cn, ce, NNZ);
  scan_partials_k<<<NCHN + NCHE, 256, 0, stream>>>(cn, ce, part, NCHN, N, NCHE, E);
  scan_apply_k<<<NCHN + NCHE, 256, 0, stream>>>(cn, ce, part, offs_n, offs_e, NCHN, N, NCHE, E);
  fill_deg_k<<<gMax, thr, 0, stream>>>(offs_n, offs_e, Dn_inv, De_inv,
                                       cur_be, cur_bn, N, E, NBE, NBN);
  partition2_k<<<gNNZ, thr, 0, stream>>>(node_idx, edge_idx, cur_be, cur_bn, SE, SN, NNZ);
  scatter_both_k<<<NBE + NBN, 256, 0, stream>>>(SE, offs_e, cur_be, listE, E, NBE,
                                                SN, offs_n, cur_bn, listN, N);

  // ---- fused dual-encoder ----
  gather_edge_k<0><<<gGatE, 256, 0, stream>>>(tb, offs_e, listE, De_inv, e1_bn2e, e2_bn2e,
                                              alphap, e_fullb, nullptr, nullptr, E);
  gather_node_k<<<gGatN, 256, 0, stream>>>(e_fullb, tb, offs_n, listN, Dn_inv, e1_bn2e, e2_bn2e,
                                           alphap, thb, N);
  gemm_fuse_hid_k<<<NT, 256, 0, stream>>>(thb, WP(2), e1_be2n, WP(1),
                                          WP(6), e2_be2n, WP(5), alphap, tb, N);
  gather_edge_k<1><<<gGatE, 256, 0, stream>>>(tb, offs_e, listE, De_inv, e1_bn2e + DD, e2_bn2e + DD,
                                              alphap, e_fullb, e1o, e2o, E);
  gather_node_k<<<gGatN, 256, 0, stream>>>(e_fullb, tb, offs_n, listN, Dn_inv, e1_bn2e + DD, e2_bn2e + DD,
                                           alphap, aggb, N);
  enc_final_k<<<NT, 256, 0, stream>>>(aggb, WP(3), e1_be2n + DD, WP(7), e2_be2n + DD,
                                      alphap, n1, n2, n1b, n2b, nn1, N);

  // ---- fully-fused decoders (round-11 shape) ----
  dim3 gDec(NT, 2);
  dec_fused_k<<<gDec, 256, 0, stream>>>(n1b, n2b, aggb,
                                        WP(10), WP(8), d1_b, WP(11), WP(9), d1_b + DD,
                                        WP(14), WP(12), d2_b, WP(15), WP(13), d2_b + DD,
                                        alphap, x11, x22, x12, x21, N);
}

// Round 14
// 566.429 us; speedup vs baseline: 1.2586x; 1.0333x over previous
//
#include <hip/hip_runtime.h>

#define DD 128

typedef __attribute__((ext_vector_type(8))) short bh8;       // 8 bf16 (as i16 bits)
typedef __attribute__((ext_vector_type(8))) unsigned short us8;
typedef __attribute__((ext_vector_type(4))) float f4;
typedef unsigned int u32;
typedef unsigned short u16;

__device__ __forceinline__ u16 tob(float f) {           // fp32 -> bf16 RNE
  u32 u = __builtin_bit_cast(u32, f);
  u += 0x7FFFu + ((u >> 16) & 1u);
  return (u16)(u >> 16);
}
__device__ __forceinline__ float fb(u16 h) { return __builtin_bit_cast(float, (u32)h << 16); }

// ================= CSR build (real edges only; self-loops analytic) =================

__global__ __launch_bounds__(256) void init_counts_k(int* cn, int* ce, int N, int E) {
  int g = blockIdx.x * blockDim.x + threadIdx.x;
  if (g < E) ce[g] = 0;
  if (g < N) cn[g] = 0;
}

// ---- parallel hierarchical exclusive scan (chunks of 1024) ----

__global__ __launch_bounds__(256) void scan_partials_k(const int* __restrict__ cn, const int* __restrict__ ce,
                                                       int* part, int NCHN, int N, int NCHE, int E) {
  __shared__ int red[256];
  int b = blockIdx.x, tid = threadIdx.x;
  const int* cnt = (b < NCHN) ? cn : ce;
  int n = (b < NCHN) ? N : E;
  int base = ((b < NCHN) ? b : (b - NCHN)) << 10;
  int i0 = base + tid * 4;
  int s = 0;
  #pragma unroll
  for (int j = 0; j < 4; ++j) { int i = i0 + j; if (i < n) s += cnt[i]; }
  red[tid] = s; __syncthreads();
  for (int off = 128; off > 0; off >>= 1) {
    if (tid < off) red[tid] += red[tid + off];
    __syncthreads();
  }
  if (tid == 0) part[b] = red[0];
}

__device__ __forceinline__ int blk_excl_scan(int s, int tid, int* sums) {
  sums[tid] = s; __syncthreads();
  for (int off = 1; off < 256; off <<= 1) {
    int t = (tid >= off) ? sums[tid - off] : 0;
    __syncthreads();
    sums[tid] += t;
    __syncthreads();
  }
  int ex = sums[tid] - s;
  __syncthreads();
  return ex;
}

// scan_apply with inlined chunk-prefix (part[] holds RAW chunk sums)
__global__ __launch_bounds__(256) void scan_apply_k(const int* __restrict__ cn, const int* __restrict__ ce,
                                                    const int* __restrict__ part,
                                                    int* offs_n, int* offs_e,
                                                    int NCHN, int N, int NCHE, int E) {
  __shared__ int sums[256];
  __shared__ int base_s;
  int b = blockIdx.x, tid = threadIdx.x;
  const bool isN = b < NCHN;
  const int* cnt = isN ? cn : ce;
  int* offs = isN ? offs_n : offs_e;
  int n = isN ? N : E;
  int nch = isN ? NCHN : NCHE;
  int c = isN ? b : b - NCHN;
  const int* pbase = isN ? part : part + NCHN;
  {
    int v = (tid < nch) ? pbase[tid] : 0;
    int ex = blk_excl_scan(v, tid, sums);
    if (tid == c) base_s = ex;
  }
  __syncthreads();
  int base = (c << 10);
  int i0 = base + tid * 4;
  int v[4]; int s = 0;
  #pragma unroll
  for (int j = 0; j < 4; ++j) { int i = i0 + j; int t = (i < n) ? cnt[i] : 0; v[j] = t; s += t; }
  int ex = blk_excl_scan(s, tid, sums);
  int run = base_s + ex;
  #pragma unroll
  for (int j = 0; j < 4; ++j) { int i = i0 + j; if (i < n) offs[i] = run; run += v[j]; }
  if (tid == 255 && base + 1024 >= n) offs[n] = run;
}

__global__ __launch_bounds__(256) void fill_deg_k(const int* __restrict__ offs_n, const int* __restrict__ offs_e,
                                                  float* Dn_inv, float* De_inv,
                                                  int* cur_be, int* cur_bn,
                                                  int N, int E, int NBE, int NBN) {
  int g = blockIdx.x * blockDim.x + threadIdx.x;
  if (g < E) {
    int b = offs_e[g], e = offs_e[g + 1];
    De_inv[g] = (e > b) ? 1.0f / (float)(e - b) : 0.0f;
  }
  if (g < N) {
    int b = offs_n[g], e = offs_n[g + 1];
    Dn_inv[g] = 1.0f / (float)(e - b + 1);   // +1 self loop
  }
  if (g < NBE) {
    int r1 = (g + 1) * 32; if (r1 > E) r1 = E;
    int o0 = offs_e[g * 32], o1 = offs_e[r1];
    int C = o1 - o0, base = 8 * o0;
    #pragma unroll
    for (int k = 0; k < 8; ++k) cur_be[g * 8 + k] = base + k * C;
  }
  if (g < NBN) {
    int r1 = (g + 1) * 32; if (r1 > N) r1 = N;
    int o0 = offs_n[g * 32], o1 = offs_n[r1];
    int C = o1 - o0, base = 8 * o0;
    #pragma unroll
    for (int k = 0; k < 8; ++k) cur_bn[g * 8 + k] = base + k * C;
  }
}

__global__ __launch_bounds__(256) void partition2_k(const int* __restrict__ ni, const int* __restrict__ ei,
                                                    int* cur_be, int* cur_bn,
                                                    u32* __restrict__ SE, u32* __restrict__ SN, int nnz) {
  int xcd;
  asm volatile("s_getreg_b32 %0, hwreg(HW_REG_XCC_ID)" : "=s"(xcd));
  xcd &= 7;
  int stride = gridDim.x * blockDim.x;
  for (int j = blockIdx.x * blockDim.x + threadIdx.x; j < nnz; j += stride) {
    int n = ni[j], e = ei[j];
    int pe = atomicAdd(&cur_be[(e >> 5) * 8 + xcd], 1);
    SE[pe] = ((u32)(e & 31) << 17) | (u32)n;
    int pn = atomicAdd(&cur_bn[(n >> 5) * 8 + xcd], 1);
    SN[pn] = ((u32)(n & 31) << 17) | (u32)e;
  }
}

__device__ __forceinline__ void scatter_body(const u32* __restrict__ S, const int* __restrict__ offs,
                                             const int* __restrict__ cur_b,
                                             int* __restrict__ list, int nRows, int b, int tid, int* cur) {
  const int i0 = b << 5;
  if (tid < 32) {
    int row = i0 + tid;
    cur[tid] = (row < nRows) ? offs[row] : 0;
  }
  __syncthreads();
  int r1 = i0 + 32; if (r1 > nRows) r1 = nRows;
  const int o0 = offs[i0];
  const int C = offs[r1] - o0;
  #pragma unroll 1
  for (int k = 0; k < 8; ++k) {
    int sbeg = 8 * o0 + k * C;
    int send = cur_b[b * 8 + k];
    for (int i = sbeg + tid; i < send; i += 256) {
      u32 v = S[i];
      int pos = atomicAdd(&cur[v >> 17], 1);
      list[pos] = (int)(v & 0x1FFFFu);
    }
  }
}

__global__ __launch_bounds__(256) void scatter_both_k(const u32* SE, const int* offs_e, const int* cur_be,
                                                      int* listE, int E, int NBE,
                                                      const u32* SN, const int* offs_n, const int* cur_bn,
                                                      int* listN, int N) {
  __shared__ int cur[32];
  int b = blockIdx.x, tid = threadIdx.x;
  if (b < NBE) scatter_body(SE, offs_e, cur_be, listE, E, b, tid, cur);
  else         scatter_body(SN, offs_n, cur_bn, listN, N, b - NBE, tid, cur);
}

// ================= gathers (width 256, bf16, split-wave: 16B/lane) =================

__device__ __forceinline__ void acc8(float a[8], us8 v) {
  #pragma unroll
  for (int j = 0; j < 8; ++j) a[j] += fb(v[j]);
}

template<int SPLIT>
__global__ __launch_bounds__(256) void gather_edge_k(const u16* __restrict__ srcb,
                                                     const int* __restrict__ offs, const int* __restrict__ list,
                                                     const float* __restrict__ De_inv,
                                                     const float* __restrict__ b1, const float* __restrict__ b2,
                                                     const float* __restrict__ alphap,
                                                     u16* __restrict__ e_fullb,
                                                     float* __restrict__ d2a, float* __restrict__ d2b, int E) {
  const int wave = threadIdx.x >> 6, lane = threadIdx.x & 63;
  const int row = blockIdx.x * 4 + wave;
  if (row >= E) return;
  const int half = lane >> 5, cl = lane & 31;
  const int c8 = cl * 8;
  const int beg = offs[row], end = offs[row + 1];
  float a0[8] = {0,0,0,0,0,0,0,0}, a1[8] = {0,0,0,0,0,0,0,0};
  int i = beg + half;
  for (; i + 2 < end; i += 4) {
    us8 v0 = *(const us8*)&srcb[(size_t)list[i] * 256 + c8];
    us8 v1 = *(const us8*)&srcb[(size_t)list[i + 2] * 256 + c8];
    acc8(a0, v0); acc8(a1, v1);
  }
  if (i < end) acc8(a0, *(const us8*)&srcb[(size_t)list[i] * 256 + c8]);
  float s[8];
  #pragma unroll
  for (int j = 0; j < 8; ++j) s[j] = a0[j] + a1[j];
  #pragma unroll
  for (int j = 0; j < 8; ++j) s[j] += __shfl_xor(s[j], 32);
  if (half == 0) {
    float sc = De_inv[row];
    const float* bp = (c8 < 128) ? (b1 + c8) : (b2 + c8 - 128);
    float4 bt0 = *(const float4*)bp;
    float4 bt1 = *(const float4*)(bp + 4);
    float bb[8] = {bt0.x, bt0.y, bt0.z, bt0.w, bt1.x, bt1.y, bt1.z, bt1.w};
    float al = *alphap;
    us8 ob;
    float ov[8];
    #pragma unroll
    for (int j = 0; j < 8; ++j) {
      float v = sc * s[j] + bb[j];
      v = (v >= 0.f) ? v : al * v;
      ov[j] = v; ob[j] = tob(v);
    }
    *(us8*)&e_fullb[(size_t)row * 256 + c8] = ob;
    if constexpr (SPLIT == 1) {
      float* dp = (c8 < 128) ? &d2a[(size_t)row * DD + c8] : &d2b[(size_t)row * DD + c8 - 128];
      float4 w0 = {ov[0], ov[1], ov[2], ov[3]};
      float4 w1 = {ov[4], ov[5], ov[6], ov[7]};
      *(float4*)dp = w0;
      *(float4*)(dp + 4) = w1;
    }
  }
}

__global__ __launch_bounds__(256) void gather_node_k(const u16* __restrict__ e_fullb,
                                                     const u16* __restrict__ tb,
                                                     const int* __restrict__ offs, const int* __restrict__ list,
                                                     const float* __restrict__ Dn_inv,
                                                     const float* __restrict__ b1, const float* __restrict__ b2,
                                                     const float* __restrict__ alphap,
                                                     u16* __restrict__ dstb, int N) {
  const int wave = threadIdx.x >> 6, lane = threadIdx.x & 63;
  const int row = blockIdx.x * 4 + wave;
  if (row >= N) return;
  const int half = lane >> 5, cl = lane & 31;
  const int c8 = cl * 8;
  const int beg = offs[row], end = offs[row + 1];
  float a0[8] = {0,0,0,0,0,0,0,0}, a1[8] = {0,0,0,0,0,0,0,0};
  int i = beg + half;
  for (; i + 2 < end; i += 4) {
    us8 v0 = *(const us8*)&e_fullb[(size_t)list[i] * 256 + c8];
    us8 v1 = *(const us8*)&e_fullb[(size_t)list[i + 2] * 256 + c8];
    acc8(a0, v0); acc8(a1, v1);
  }
  if (i < end) acc8(a0, *(const us8*)&e_fullb[(size_t)list[i] * 256 + c8]);
  float s[8];
  #pragma unroll
  for (int j = 0; j < 8; ++j) s[j] = a0[j] + a1[j];
  #pragma unroll
  for (int j = 0; j < 8; ++j) s[j] += __shfl_xor(s[j], 32);
  if (half == 0) {
    us8 tv = *(const us8*)&tb[(size_t)row * 256 + c8];
    const float* bp = (c8 < 128) ? (b1 + c8) : (b2 + c8 - 128);
    float4 bt0 = *(const float4*)bp;
    float4 bt1 = *(const float4*)(bp + 4);
    float bb[8] = {bt0.x, bt0.y, bt0.z, bt0.w, bt1.x, bt1.y, bt1.z, bt1.w};
    float al = *alphap;
    float sc = Dn_inv[row];
    us8 ob;
    #pragma unroll
    for (int j = 0; j < 8; ++j) {
      float sv = fb(tv[j]) + bb[j];
      sv = (sv >= 0.f) ? sv : al * sv;
      ob[j] = tob(sc * (sv + s[j]));
    }
    *(us8*)&dstb[(size_t)row * 256 + c8] = ob;
  }
}

// ================= weight prep =================

struct WPtrs { const float* p[16]; };

__global__ __launch_bounds__(256) void prep_w_k(WPtrs wp, char* dst) {
  int m = blockIdx.x >> 3, s = blockIdx.x & 7;
  const float* W = wp.p[m];
  int t = threadIdx.x;
  int n = t & 127;
  int k0 = s * 16 + (t >> 7) * 8;
  us8 vhi, vlo;
  #pragma unroll
  for (int j = 0; j < 8; ++j) {
    float x = W[(size_t)(k0 + j) * DD + n];
    u32 ux = __builtin_bit_cast(u32, x);
    float hf = __builtin_bit_cast(float, ux & 0xFFFF0000u);
    float l = x - hf;
    vhi[j] = (u16)(ux >> 16);
    vlo[j] = (u16)(__builtin_bit_cast(u32, l) >> 16);
  }
  char* base = dst + (size_t)m * 65536;
  int byte = n * 256 + k0 * 2;
  byte ^= (n & 7) << 4;
  *(us8*)(base + byte) = vhi;
  *(us8*)(base + 32768 + byte) = vlo;
}

// ================= MFMA machinery =================

__device__ __forceinline__ void stage_w(const char* gsrc, char* lds, int tid) {
  int wave = tid >> 6, lane = tid & 63;
  #pragma unroll
  for (int i = 0; i < 16; ++i) {
    int off = (wave * 16 + i) * 1024;
    __builtin_amdgcn_global_load_lds(
        (const __attribute__((address_space(1))) u32*)(gsrc + off + lane * 16),
        (__attribute__((address_space(3))) u32*)(lds + off), 16, 0, 0);
  }
}

// hi-only 32KB stage
__device__ __forceinline__ void stage_w32(const char* gsrc, char* lds, int tid) {
  int wave = tid >> 6, lane = tid & 63;
  #pragma unroll
  for (int i = 0; i < 8; ++i) {
    int off = (wave * 8 + i) * 1024;
    __builtin_amdgcn_global_load_lds(
        (const __attribute__((address_space(1))) u32*)(gsrc + off + lane * 16),
        (__attribute__((address_space(3))) u32*)(lds + off), 16, 0, 0);
  }
}

__device__ __forceinline__ void split8(const float vs[8], bh8& hi, bh8& lo) {
  #pragma unroll
  for (int j = 0; j < 8; ++j) {
    u32 u = __builtin_bit_cast(u32, vs[j]);
    float hf = __builtin_bit_cast(float, u & 0xFFFF0000u);
    float l = vs[j] - hf;
    hi[j] = (short)(u >> 16);
    lo[j] = (short)(__builtin_bit_cast(u32, l) >> 16);
  }
}

__device__ __forceinline__ void mk_afrag(const float* rowp, int koff, bh8& hi, bh8& lo) {
  float4 v0 = *(const float4*)(rowp + koff);
  float4 v1 = *(const float4*)(rowp + koff + 4);
  float vs[8] = {v0.x, v0.y, v0.z, v0.w, v1.x, v1.y, v1.z, v1.w};
  split8(vs, hi, lo);
}

// fp32-A split-3 path (full W)
__device__ __forceinline__ void mfma_ks(const bh8& ahi, const bh8& alo, const char* Wl,
                                        int ks, int lane, f4 acc[8]) {
  const int koff0 = (lane >> 4) * 8;
  const int k2 = (ks * 32 + koff0) * 2;
  #pragma unroll
  for (int cb = 0; cb < 8; ++cb) {
    int n = cb * 16 + (lane & 15);
    int byte = (n * 256 + k2) ^ ((n & 7) << 4);
    bh8 bhiF = *(const bh8*)(Wl + byte);
    bh8 bloF = *(const bh8*)(Wl + 32768 + byte);
    acc[cb] = __builtin_amdgcn_mfma_f32_16x16x32_bf16(ahi, bhiF, acc[cb], 0, 0, 0);
    acc[cb] = __builtin_amdgcn_mfma_f32_16x16x32_bf16(ahi, bloF, acc[cb], 0, 0, 0);
    acc[cb] = __builtin_amdgcn_mfma_f32_16x16x32_bf16(alo, bhiF, acc[cb], 0, 0, 0);
  }
}

// fp32-A, hi-only W (2 MFMA): exact A, quantized W
__device__ __forceinline__ void mfma_ks_hi2(const bh8& ahi, const bh8& alo, const char* Wl,
                                            int ks, int lane, f4 acc[8]) {
  const int koff0 = (lane >> 4) * 8;
  const int k2 = (ks * 32 + koff0) * 2;
  #pragma unroll
  for (int cb = 0; cb < 8; ++cb) {
    int n = cb * 16 + (lane & 15);
    int byte = (n * 256 + k2) ^ ((n & 7) << 4);
    bh8 bhiF = *(const bh8*)(Wl + byte);
    acc[cb] = __builtin_amdgcn_mfma_f32_16x16x32_bf16(ahi, bhiF, acc[cb], 0, 0, 0);
    acc[cb] = __builtin_amdgcn_mfma_f32_16x16x32_bf16(alo, bhiF, acc[cb], 0, 0, 0);
  }
}

// bf16-A exact path (2 MFMA, full W)
__device__ __forceinline__ void mfma_ks_bf(const bh8& a, const char* Wl,
                                           int ks, int lane, f4 acc[8]) {
  const int koff0 = (lane >> 4) * 8;
  const int k2 = (ks * 32 + koff0) * 2;
  #pragma unroll
  for (int cb = 0; cb < 8; ++cb) {
    int n = cb * 16 + (lane & 15);
    int byte = (n * 256 + k2) ^ ((n & 7) << 4);
    bh8 bhiF = *(const bh8*)(Wl + byte);
    bh8 bloF = *(const bh8*)(Wl + 32768 + byte);
    acc[cb] = __builtin_amdgcn_mfma_f32_16x16x32_bf16(a, bhiF, acc[cb], 0, 0, 0);
    acc[cb] = __builtin_amdgcn_mfma_f32_16x16x32_bf16(a, bloF, acc[cb], 0, 0, 0);
  }
}

// bf16-A, hi-only W (1 MFMA)
__device__ __forceinline__ void mfma_ks_bfhi(const bh8& a, const char* Wl,
                                             int ks, int lane, f4 acc[8]) {
  const int koff0 = (lane >> 4) * 8;
  const int k2 = (ks * 32 + koff0) * 2;
  #pragma unroll
  for (int cb = 0; cb < 8; ++cb) {
    int n = cb * 16 + (lane & 15);
    int byte = (n * 256 + k2) ^ ((n & 7) << 4);
    bh8 bhiF = *(const bh8*)(Wl + byte);
    acc[cb] = __builtin_amdgcn_mfma_f32_16x16x32_bf16(a, bhiF, acc[cb], 0, 0, 0);
  }
}

__device__ __forceinline__ void mfma_passS_hi2(const float* __restrict__ A, size_t astride, int acoff,
                                               const char* Wl, int rbase, int nrows, int lane, f4 acc[8]) {
  int r = rbase + (lane & 15);
  if (r >= nrows) r = nrows - 1;
  const float* rowp = A + (size_t)r * astride + acoff;
  const int koff0 = (lane >> 4) * 8;
  #pragma unroll
  for (int ks = 0; ks < 4; ++ks) {
    bh8 ahi, alo;
    mk_afrag(rowp, ks * 32 + koff0, ahi, alo);
    mfma_ks_hi2(ahi, alo, Wl, ks, lane, acc);
  }
}

__device__ __forceinline__ void mfma_passB(const u16* __restrict__ A, size_t astride, int acoff,
                                           const char* Wl, int rbase, int nrows, int lane, f4 acc[8]) {
  int r = rbase + (lane & 15);
  if (r >= nrows) r = nrows - 1;
  const u16* rowp = A + (size_t)r * astride + acoff;
  const int koff0 = (lane >> 4) * 8;
  #pragma unroll
  for (int ks = 0; ks < 4; ++ks) {
    bh8 a = __builtin_bit_cast(bh8, *(const us8*)(rowp + ks * 32 + koff0));
    mfma_ks_bf(a, Wl, ks, lane, acc);
  }
}

__device__ __forceinline__ void mfma_passB_hi(const u16* __restrict__ A, size_t astride, int acoff,
                                              const char* Wl, int rbase, int nrows, int lane, f4 acc[8]) {
  int r = rbase + (lane & 15);
  if (r >= nrows) r = nrows - 1;
  const u16* rowp = A + (size_t)r * astride + acoff;
  const int koff0 = (lane >> 4) * 8;
  #pragma unroll
  for (int ks = 0; ks < 4; ++ks) {
    bh8 a = __builtin_bit_cast(bh8, *(const us8*)(rowp + ks * 32 + koff0));
    mfma_ks_bfhi(a, Wl, ks, lane, acc);
  }
}

struct AFragB { bh8 a[4]; };

__device__ __forceinline__ void load_afragB(const u16* __restrict__ A, size_t astride, int acoff,
                                            int rbase, int nrows, int lane, AFragB& f) {
  int r = rbase + (lane & 15);
  if (r >= nrows) r = nrows - 1;
  const u16* rowp = A + (size_t)r * astride + acoff;
  const int koff0 = (lane >> 4) * 8;
  #pragma unroll
  for (int ks = 0; ks < 4; ++ks)
    f.a[ks] = __builtin_bit_cast(bh8, *(const us8*)(rowp + ks * 32 + koff0));
}

__device__ __forceinline__ void mfma_pass_fragB(const AFragB& f, const char* Wl, int lane, f4 acc[8]) {
  #pragma unroll
  for (int ks = 0; ks < 4; ++ks) mfma_ks_bf(f.a[ks], Wl, ks, lane, acc);
}

__device__ __forceinline__ void mfma_pass_fragB_hi(const AFragB& f, const char* Wl, int lane, f4 acc[8]) {
  #pragma unroll
  for (int ks = 0; ks < 4; ++ks) mfma_ks_bfhi(f.a[ks], Wl, ks, lane, acc);
}

// ---- LDS T-tile (64 rows x 128 bf16, XOR-swizzled) ----

__device__ __forceinline__ void acc_to_T(f4 acc[8], const float* bias, float al,
                                         char* Tb, int wave, int lane) {
  const int cidx = lane & 15;
  float b8[8];
  #pragma unroll
  for (int cb = 0; cb < 8; ++cb) b8[cb] = bias[cb * 16 + cidx];
  #pragma unroll
  for (int q = 0; q < 4; ++q) {
    int row = wave * 16 + (lane >> 4) * 4 + q;
    #pragma unroll
    for (int cb = 0; cb < 8; ++cb) {
      float v = acc[cb][q] + b8[cb];
      v = (v >= 0.f) ? v : al * v;
      int byte = (row * 256 + (cb * 16 + cidx) * 2) ^ ((row & 7) << 4);
      *(u16*)(Tb + byte) = tob(v);
    }
  }
}

__device__ __forceinline__ void load_fT(const char* Tb, int wave, int lane, AFragB& f) {
  const int row = wave * 16 + (lane & 15);
  const int koff0 = (lane >> 4) * 8;
  #pragma unroll
  for (int ks = 0; ks < 4; ++ks) {
    int byte = (row * 256 + (ks * 32 + koff0) * 2) ^ ((row & 7) << 4);
    f.a[ks] = __builtin_bit_cast(bh8, *(const us8*)(Tb + byte));
  }
}

// MODE 0: raw; MODE 1: +bias +prelu.  OBF: write bf16 instead of fp32.
template<int MODE, int OBF>
__device__ __forceinline__ void epilogueS(f4 acc[8], const float* bias, const float* alphap,
                                          void* outp, size_t ostride, int ocoff,
                                          int rbase, int nrows, int lane) {
  float al = 0.f;
  if constexpr (MODE == 1) al = *alphap;
  const int cidx = lane & 15;
  int rq = rbase + (lane >> 4) * 4;
  float b8[8];
  if constexpr (MODE == 1) {
    #pragma unroll
    for (int cb = 0; cb < 8; ++cb) b8[cb] = bias[cb * 16 + cidx];
  }
  #pragma unroll
  for (int q = 0; q < 4; ++q) {
    int row = rq + q;
    if (row < nrows) {
      #pragma unroll
      for (int cb = 0; cb < 8; ++cb) {
        float v = acc[cb][q];
        if constexpr (MODE == 1) { v += b8[cb]; v = (v >= 0.f) ? v : al * v; }
        if constexpr (OBF == 1) {
          u16* op = (u16*)outp + (size_t)row * ostride + ocoff + cidx;
          op[cb * 16] = tob(v);
        } else {
          float* op = (float*)outp + (size_t)row * ostride + ocoff + cidx;
          op[cb * 16] = v;
        }
      }
    }
  }
}

#define ACC_ZERO(acc) { _Pragma("unroll") for (int cb = 0; cb < 8; ++cb) acc[cb] = {0.f, 0.f, 0.f, 0.f}; }

// ================= GEMM kernels =================

// combo: blocks [0,NT) = GEMM1 (hi-only W, exact A); blocks [NT, NT+HB) = histogram
__global__ __launch_bounds__(256, 2) void combo1_k(const float* __restrict__ x, const char* W0,
                                                   const float* __restrict__ xx, const char* W4,
                                                   u16* __restrict__ tb, int nrows, int NT,
                                                   const int* __restrict__ ni, const int* __restrict__ ei,
                                                   int* cn, int* ce, int nnz) {
  __shared__ char Wl[32768];
  if ((int)blockIdx.x < NT) {
    const int wave = threadIdx.x >> 6, lane = threadIdx.x & 63;
    const int rbase = blockIdx.x * 64 + wave * 16;
    f4 acc[8];
    stage_w32(W0, Wl, threadIdx.x);
    __syncthreads();
    ACC_ZERO(acc);
    mfma_passS_hi2(x, DD, 0, Wl, rbase, nrows, lane, acc);
    epilogueS<0, 1>(acc, nullptr, nullptr, tb, 256, 0, rbase, nrows, lane);
    __syncthreads();
    stage_w32(W4, Wl, threadIdx.x);
    __syncthreads();
    ACC_ZERO(acc);
    mfma_passS_hi2(xx, DD, 0, Wl, rbase, nrows, lane, acc);
    epilogueS<0, 1>(acc, nullptr, nullptr, tb, 256, 128, rbase, nrows, lane);
  } else {
    int nb = gridDim.x - NT;
    int stride = nb * 256;
    for (int j = ((int)blockIdx.x - NT) * 256 + (int)threadIdx.x; j < nnz; j += stride) {
      atomicAdd(&cn[ni[j]], 1);
      atomicAdd(&ce[ei[j]], 1);
    }
  }
}

// fused hidden + GEMM3 per half, hi-only weights, H0/H1 double-buffer + dedicated T:
// T = prelu(thb_h@We2n_h + be2n_h); tb_h = bf16(T@Wn2e_h1)
__global__ __launch_bounds__(256, 2) void gemm_fuse_hid_k(const u16* __restrict__ thb,
                                                          const char* W20, const float* b20, const char* W21,
                                                          const char* W60, const float* b60, const char* W61,
                                                          const float* __restrict__ alphap,
                                                          u16* __restrict__ tb_out, int nrows) {
  __shared__ char Wl[81920];           // H0 [0,32K), H1 [32K,64K), T [64K,80K)
  char* H0 = Wl;
  char* H1 = Wl + 32768;
  char* Tb = Wl + 65536;
  const int wave = threadIdx.x >> 6, lane = threadIdx.x & 63;
  const int rbase = blockIdx.x * 64 + wave * 16;
  const float al = *alphap;
  f4 acc[8];
  AFragB fT;
  #pragma unroll 1
  for (int h = 0; h < 2; ++h) {
    if (h) __syncthreads();            // protect H0/H1/T from previous iteration's readers
    stage_w32(h ? W60 : W20, H0, threadIdx.x);
    __syncthreads();
    stage_w32(h ? W61 : W21, H1, threadIdx.x);   // issue-early: loads fly during MFMA below
    ACC_ZERO(acc);
    mfma_passB_hi(thb, 256, h * 128, H0, rbase, nrows, lane, acc);
    __syncthreads();                   // drains H1 load; all H0 reads done
    acc_to_T(acc, h ? b60 : b20, al, Tb, wave, lane);
    __syncthreads();
    load_fT(Tb, wave, lane, fT);
    ACC_ZERO(acc);
    mfma_pass_fragB_hi(fT, H1, lane, acc);
    epilogueS<0, 1>(acc, nullptr, nullptr, tb_out, 256, h * 128, rbase, nrows, lane);
  }
}

// encoder final (A = aggb bf16, FULL weights): n1/n2 fp32 + nn1 fp32 + bf16 copies
__global__ __launch_bounds__(256, 2) void enc_final_k(const u16* __restrict__ aggb, const char* W1, const float* b1_,
                                                      const char* W2, const float* b2_,
                                                      const float* __restrict__ alphap,
                                                      float* __restrict__ n1, float* __restrict__ n2,
                                                      u16* __restrict__ n1b, u16* __restrict__ n2b,
                                                      float* __restrict__ nn1, int nrows) {
  __shared__ char Wl[65536];
  const int wave = threadIdx.x >> 6, lane = threadIdx.x & 63;
  const int rbase = blockIdx.x * 64 + wave * 16;
  const int cidx = lane & 15;
  f4 acc[8];
  float al = *alphap;
  #pragma unroll 1
  for (int h = 0; h < 2; ++h) {
    if (h) __syncthreads();
    stage_w(h ? W2 : W1, Wl, threadIdx.x);
    __syncthreads();
    const float* bp = h ? b2_ : b1_;
    float* nout = h ? n2 : n1;
    u16* nbout = h ? n2b : n1b;
    float b8[8];
    #pragma unroll
    for (int cb = 0; cb < 8; ++cb) b8[cb] = bp[cb * 16 + cidx];
    ACC_ZERO(acc);
    mfma_passB(aggb, 256, h * 128, Wl, rbase, nrows, lane, acc);
    int rq = rbase + (lane >> 4) * 4;
    #pragma unroll
    for (int q = 0; q < 4; ++q) {
      int row = rq + q;
      if (row < nrows) {
        float* op = nout + (size_t)row * DD + cidx;
        float* op2 = nn1 + (size_t)row * 256 + h * 128 + cidx;
        u16* op3 = nbout + (size_t)row * DD + cidx;
        #pragma unroll
        for (int cb = 0; cb < 8; ++cb) {
          float v = acc[cb][q] + b8[cb];
          v = (v >= 0.f) ? v : al * v;
          op[cb * 16] = v;
          op2[cb * 16] = v;
          op3[cb * 16] = tob(v);
        }
      }
    }
  }
}

// fully-fused decoder (FULL weights; round-13 proven shape): 1 tile, y = n-stream, serial d-stream loop.
__global__ __launch_bounds__(256, 2) void dec_fused_k(const u16* __restrict__ n1b, const u16* __restrict__ n2b,
                                                      const u16* __restrict__ aggb,
                                                      const char* Wx10, const char* We10, const float* b1_0,
                                                      const char* Wx11, const char* We11, const float* b1_1,
                                                      const char* Wx20, const char* We20, const float* b2_0,
                                                      const char* Wx21, const char* We21, const float* b2_1,
                                                      const float* __restrict__ alphap,
                                                      float* __restrict__ x11, float* __restrict__ x22,
                                                      float* __restrict__ x12, float* __restrict__ x21,
                                                      int nrows) {
  __shared__ char Wl[65536];
  const int y = blockIdx.y;
  const u16* xb = y ? n2b : n1b;
  float* od1 = y ? x12 : x11;
  float* od2 = y ? x21 : x22;
  const int acoff = y * 128;
  const int wave = threadIdx.x >> 6, lane = threadIdx.x & 63;
  const int rbase = blockIdx.x * 64 + wave * 16;
  const float al = *alphap;
  AFragB fx, fa, fT;
  load_afragB(xb, DD, 0, rbase, nrows, lane, fx);
  load_afragB(aggb, 256, acoff, rbase, nrows, lane, fa);
  f4 acc[8];
  #pragma unroll 1
  for (int s = 0; s < 2; ++s) {
    const char* Wx0 = s ? Wx20 : Wx10;
    const char* We0 = s ? We20 : We10;
    const char* Wx1 = s ? Wx21 : Wx11;
    const char* We1 = s ? We21 : We11;
    const float* b0 = s ? b2_0 : b1_0;
    const float* b1 = s ? b2_1 : b1_1;
    float* out = s ? od2 : od1;
    if (s) __syncthreads();
    stage_w(Wx0, Wl, threadIdx.x);
    __syncthreads();
    ACC_ZERO(acc);
    mfma_pass_fragB(fx, Wl, lane, acc);
    __syncthreads();
    stage_w(We0, Wl, threadIdx.x);
    __syncthreads();
    mfma_pass_fragB(fa, Wl, lane, acc);
    __syncthreads();
    acc_to_T(acc, b0, al, Wl, wave, lane);
    __syncthreads();
    load_fT(Wl, wave, lane, fT);
    __syncthreads();
    stage_w(Wx1, Wl, threadIdx.x);
    __syncthreads();
    ACC_ZERO(acc);
    mfma_pass_fragB(fT, Wl, lane, acc);
    __syncthreads();
    stage_w(We1, Wl, threadIdx.x);
    __syncthreads();
    mfma_pass_fragB(fa, Wl, lane, acc);
    epilogueS<1, 0>(acc, b1, alphap, out, DD, 0, rbase, nrows, lane);
  }
}

// ================= host =================

extern "C" void kernel_launch(void* const* d_in, const int* in_sizes, int n_in,
                              void* d_out, int out_size, void* d_ws, size_t ws_size,
                              hipStream_t stream) {
  const float* x        = (const float*)d_in[0];
  const float* xx       = (const float*)d_in[1];
  const int*   node_idx = (const int*)d_in[2];
  const int*   edge_idx = (const int*)d_in[3];
  const float* alphap   = (const float*)d_in[6];
  const float* e1_Wn2e  = (const float*)d_in[7];
  const float* e1_bn2e  = (const float*)d_in[8];
  const float* e1_We2n  = (const float*)d_in[9];
  const float* e1_be2n  = (const float*)d_in[10];
  const float* e2_Wn2e  = (const float*)d_in[11];
  const float* e2_bn2e  = (const float*)d_in[12];
  const float* e2_We2n  = (const float*)d_in[13];
  const float* e2_be2n  = (const float*)d_in[14];
  const float* d1_We    = (const float*)d_in[15];
  const float* d1_Wx    = (const float*)d_in[16];
  const float* d1_b     = (const float*)d_in[17];
  const float* d2_We    = (const float*)d_in[18];
  const float* d2_Wx    = (const float*)d_in[19];
  const float* d2_b     = (const float*)d_in[20];

  const int N   = in_sizes[0] / DD;
  const int NNZ = in_sizes[2];
  const int E   = (out_size - 1024 * N) / 256;
  const int NBE = (E + 31) >> 5;
  const int NBN = (N + 31) >> 5;
  const int NCHN = (N + 1023) >> 10;
  const int NCHE = (E + 1023) >> 10;

  // ---- d_out slot map ----
  float* out  = (float*)d_out;
  float* nn1  = out;
  float* n1   = out + (size_t)N * 256;
  float* e1o  = n1 + (size_t)N * DD;
  float* n2   = e1o + (size_t)E * DD;
  float* e2o  = n2 + (size_t)N * DD;
  float* x11  = e2o + (size_t)E * DD;
  float* x21  = x11 + (size_t)N * DD;
  float* x12  = x21 + (size_t)N * DD;
  float* x22  = x12 + (size_t)N * DD;

  // ---- workspace carve ----
  size_t off = 0;
  char* w0 = (char*)d_ws;
  auto carve = [&](size_t bytes) -> void* {
    void* p = (void*)(w0 + off);
    off += (bytes + 255) & ~(size_t)255;
    return p;
  };
  int* cn      = (int*)carve((size_t)N * 4);
  int* ce      = (int*)carve((size_t)E * 4);
  int* offs_n  = (int*)carve((size_t)(N + 1) * 4);
  int* offs_e  = (int*)carve((size_t)(E + 1) * 4);
  int* part    = (int*)carve((size_t)(NCHN + NCHE) * 4);
  int* listN   = (int*)carve((size_t)NNZ * 4);
  int* listE   = (int*)carve((size_t)NNZ * 4);
  float* Dn_inv = (float*)carve((size_t)N * 4);
  float* De_inv = (float*)carve((size_t)E * 4);
  char* Wprep  = (char*)carve((size_t)16 * 65536);
  u16* tb      = (u16*)carve((size_t)N * 256 * 2);
  u16* e_fullb = (u16*)carve((size_t)E * 256 * 2);
  u16* thb     = (u16*)carve((size_t)N * 256 * 2);
  u16* aggb    = (u16*)carve((size_t)N * 256 * 2);
  u16* n1b     = (u16*)carve((size_t)N * DD * 2);
  u16* n2b     = (u16*)carve((size_t)N * DD * 2);
  int* cur_be  = (int*)carve((size_t)NBE * 8 * 4);
  int* cur_bn  = (int*)carve((size_t)NBN * 8 * 4);
  u32* SE      = (u32*)carve((size_t)NNZ * 8 * 4);
  u32* SN      = (u32*)carve((size_t)NNZ * 8 * 4);

  // ---- weight prep table ----
  WPtrs wp;
  wp.p[0] = e1_Wn2e;  wp.p[1] = e1_Wn2e + DD * DD;
  wp.p[2] = e1_We2n;  wp.p[3] = e1_We2n + DD * DD;
  wp.p[4] = e2_Wn2e;  wp.p[5] = e2_Wn2e + DD * DD;
  wp.p[6] = e2_We2n;  wp.p[7] = e2_We2n + DD * DD;
  wp.p[8] = d1_We;    wp.p[9] = d1_We + DD * DD;
  wp.p[10] = d1_Wx;   wp.p[11] = d1_Wx + DD * DD;
  wp.p[12] = d2_We;   wp.p[13] = d2_We + DD * DD;
  wp.p[14] = d2_Wx;   wp.p[15] = d2_Wx + DD * DD;
  auto WP = [&](int i) -> const char* { return Wprep + (size_t)i * 65536; };

  const int thr = 256;
  const int gMax = ((N > E ? N : E) + thr - 1) / thr;
  const int NT = (N + 63) / 64;
  const int HB = 512;
  int gNNZ = (NNZ + thr - 1) / thr; if (gNNZ > 2048) gNNZ = 2048;
  const int gGatE = (E + 3) / 4;
  const int gGatN = (N + 3) / 4;

  prep_w_k<<<128, 256, 0, stream>>>(wp, Wprep);
  init_counts_k<<<gMax, thr, 0, stream>>>(cn, ce, N, E);
  // GEMM1 ∥ histogram
  combo1_k<<<NT + HB, 256, 0, stream>>>(x, WP(0), xx, WP(4), tb, N, NT,
                                        node_idx, edge_idx, cn, ce, NNZ);
  scan_partials_k<<<NCHN + NCHE, 256, 0, stream>>>(cn, ce, part, NCHN, N, NCHE, E);
  scan_apply_k<<<NCHN + NCHE, 256, 0, stream>>>(cn, ce, part, offs_n, offs_e, NCHN, N, NCHE, E);
  fill_deg_k<<<gMax, thr, 0, stream>>>(offs_n, offs_e, Dn_inv, De_inv,
                                       cur_be, cur_bn, N, E, NBE, NBN);
  partition2_k<<<gNNZ, thr, 0, stream>>>(node_idx, edge_idx, cur_be, cur_bn, SE, SN, NNZ);
  scatter_both_k<<<NBE + NBN, 256, 0, stream>>>(SE, offs_e, cur_be, listE, E, NBE,
                                                SN, offs_n, cur_bn, listN, N);

  // ---- fused dual-encoder ----
  gather_edge_k<0><<<gGatE, 256, 0, stream>>>(tb, offs_e, listE, De_inv, e1_bn2e, e2_bn2e,
                                              alphap, e_fullb, nullptr, nullptr, E);
  gather_node_k<<<gGatN, 256, 0, stream>>>(e_fullb, tb, offs_n, listN, Dn_inv, e1_bn2e, e2_bn2e,
                                           alphap, thb, N);
  gemm_fuse_hid_k<<<NT, 256, 0, stream>>>(thb, WP(2), e1_be2n, WP(1),
                                          WP(6), e2_be2n, WP(5), alphap, tb, N);
  gather_edge_k<1><<<gGatE, 256, 0, stream>>>(tb, offs_e, listE, De_inv, e1_bn2e + DD, e2_bn2e + DD,
                                              alphap, e_fullb, e1o, e2o, E);
  gather_node_k<<<gGatN, 256, 0, stream>>>(e_fullb, tb, offs_n, listN, Dn_inv, e1_bn2e + DD, e2_bn2e + DD,
                                           alphap, aggb, N);
  enc_final_k<<<NT, 256, 0, stream>>>(aggb, WP(3), e1_be2n + DD, WP(7), e2_be2n + DD,
                                      alphap, n1, n2, n1b, n2b, nn1, N);

  // ---- fully-fused decoders ----
  dim3 gDec(NT, 2);
  dec_fused_k<<<gDec, 256, 0, stream>>>(n1b, n2b, aggb,
                                        WP(10), WP(8), d1_b, WP(11), WP(9), d1_b + DD,
                                        WP(14), WP(12), d2_b, WP(15), WP(13), d2_b + DD,
                                        alphap, x11, x22, x12, x21, N);
}

// Round 15
// 558.389 us; speedup vs baseline: 1.2767x; 1.0144x over previous
//
#include <hip/hip_runtime.h>

#define DD 128

typedef __attribute__((ext_vector_type(8))) short bh8;       // 8 bf16 (as i16 bits)
typedef __attribute__((ext_vector_type(8))) unsigned short us8;
typedef __attribute__((ext_vector_type(4))) float f4;
typedef unsigned int u32;
typedef unsigned short u16;

__device__ __forceinline__ u16 tob(float f) {           // fp32 -> bf16 RNE
  u32 u = __builtin_bit_cast(u32, f);
  u += 0x7FFFu + ((u >> 16) & 1u);
  return (u16)(u >> 16);
}
__device__ __forceinline__ float fb(u16 h) { return __builtin_bit_cast(float, (u32)h << 16); }

// ================= CSR build (real edges only; self-loops analytic) =================

__global__ __launch_bounds__(256) void init_counts_k(int* cn, int* ce, int N, int E) {
  int g = blockIdx.x * blockDim.x + threadIdx.x;
  if (g < E) ce[g] = 0;
  if (g < N) cn[g] = 0;
}

__global__ __launch_bounds__(256) void scan_partials_k(const int* __restrict__ cn, const int* __restrict__ ce,
                                                       int* part, int NCHN, int N, int NCHE, int E) {
  __shared__ int red[256];
  int b = blockIdx.x, tid = threadIdx.x;
  const int* cnt = (b < NCHN) ? cn : ce;
  int n = (b < NCHN) ? N : E;
  int base = ((b < NCHN) ? b : (b - NCHN)) << 10;
  int i0 = base + tid * 4;
  int s = 0;
  #pragma unroll
  for (int j = 0; j < 4; ++j) { int i = i0 + j; if (i < n) s += cnt[i]; }
  red[tid] = s; __syncthreads();
  for (int off = 128; off > 0; off >>= 1) {
    if (tid < off) red[tid] += red[tid + off];
    __syncthreads();
  }
  if (tid == 0) part[b] = red[0];
}

__device__ __forceinline__ int blk_excl_scan(int s, int tid, int* sums) {
  sums[tid] = s; __syncthreads();
  for (int off = 1; off < 256; off <<= 1) {
    int t = (tid >= off) ? sums[tid - off] : 0;
    __syncthreads();
    sums[tid] += t;
    __syncthreads();
  }
  int ex = sums[tid] - s;
  __syncthreads();
  return ex;
}

// scan_apply FUSED: offs + inverse degrees + per-(bucket,xcd) staging cursors.
// part[] holds RAW chunk sums; buckets (32 rows) never straddle 1024-row chunks.
__global__ __launch_bounds__(256) void scan_apply_k(const int* __restrict__ cn, const int* __restrict__ ce,
                                                    const int* __restrict__ part,
                                                    int* offs_n, int* offs_e,
                                                    float* Dn_inv, float* De_inv,
                                                    int* cur_bn, int* cur_be,
                                                    int NCHN, int N, int NCHE, int E, int NBN, int NBE) {
  __shared__ int sums[256];
  __shared__ int base_s;
  int b = blockIdx.x, tid = threadIdx.x;
  const bool isN = b < NCHN;
  const int* cnt = isN ? cn : ce;
  int* offs = isN ? offs_n : offs_e;
  int n = isN ? N : E;
  int nch = isN ? NCHN : NCHE;
  int c = isN ? b : b - NCHN;
  const int* pbase = isN ? part : part + NCHN;
  {
    int v = (tid < nch) ? pbase[tid] : 0;
    int ex = blk_excl_scan(v, tid, sums);
    if (tid == c) base_s = ex;
  }
  __syncthreads();
  int base = (c << 10);
  int i0 = base + tid * 4;
  int v[4]; int s = 0;
  #pragma unroll
  for (int j = 0; j < 4; ++j) { int i = i0 + j; int t = (i < n) ? cnt[i] : 0; v[j] = t; s += t; }
  int ex = blk_excl_scan(s, tid, sums);   // sums[] now holds inclusive per-thread prefixes
  int run = base_s + ex;
  #pragma unroll
  for (int j = 0; j < 4; ++j) {
    int i = i0 + j;
    if (i < n) {
      offs[i] = run;
      if (isN) Dn_inv[i] = 1.0f / (float)(v[j] + 1);            // +1 self loop
      else     De_inv[i] = (v[j] > 0) ? 1.0f / (float)v[j] : 0.0f;
      run += v[j];
    }
  }
  if (tid == 255 && base + 1024 >= n) offs[n] = run;
  // bucket cursors: bucket = 32 rows = 8 threads; 32 buckets per chunk
  if (tid < 32) {
    int gb = c * 32 + tid;
    int NB = isN ? NBN : NBE;
    if (gb < NB) {
      int t0 = tid * 8;
      int pre = t0 ? sums[t0 - 1] : 0;
      int o0 = base_s + pre;
      int C = sums[t0 + 7] - pre;
      int* cur = isN ? cur_bn : cur_be;
      int b8 = 8 * o0;
      #pragma unroll
      for (int k = 0; k < 8; ++k) cur[gb * 8 + k] = b8 + k * C;
    }
  }
}

__device__ __forceinline__ void scatter_body(const u32* __restrict__ S, const int* __restrict__ offs,
                                             const int* __restrict__ cur_b,
                                             int* __restrict__ list, int nRows, int b, int tid, int* cur) {
  const int i0 = b << 5;
  if (tid < 32) {
    int row = i0 + tid;
    cur[tid] = (row < nRows) ? offs[row] : 0;
  }
  __syncthreads();
  int r1 = i0 + 32; if (r1 > nRows) r1 = nRows;
  const int o0 = offs[i0];
  const int C = offs[r1] - o0;
  #pragma unroll 1
  for (int k = 0; k < 8; ++k) {
    int sbeg = 8 * o0 + k * C;
    int send = cur_b[b * 8 + k];
    for (int i = sbeg + tid; i < send; i += 256) {
      u32 v = S[i];
      int pos = atomicAdd(&cur[v >> 17], 1);
      list[pos] = (int)(v & 0x1FFFFu);
    }
  }
}

__global__ __launch_bounds__(256) void scatter_both_k(const u32* SE, const int* offs_e, const int* cur_be,
                                                      int* listE, int E, int NBE,
                                                      const u32* SN, const int* offs_n, const int* cur_bn,
                                                      int* listN, int N) {
  __shared__ int cur[32];
  int b = blockIdx.x, tid = threadIdx.x;
  if (b < NBE) scatter_body(SE, offs_e, cur_be, listE, E, b, tid, cur);
  else         scatter_body(SN, offs_n, cur_bn, listN, N, b - NBE, tid, cur);
}

// ================= gathers (width 256, bf16, split-wave: 16B/lane) =================

__device__ __forceinline__ void acc8(float a[8], us8 v) {
  #pragma unroll
  for (int j = 0; j < 8; ++j) a[j] += fb(v[j]);
}

template<int SPLIT>
__global__ __launch_bounds__(256) void gather_edge_k(const u16* __restrict__ srcb,
                                                     const int* __restrict__ offs, const int* __restrict__ list,
                                                     const float* __restrict__ De_inv,
                                                     const float* __restrict__ b1, const float* __restrict__ b2,
                                                     const float* __restrict__ alphap,
                                                     u16* __restrict__ e_fullb,
                                                     float* __restrict__ d2a, float* __restrict__ d2b, int E) {
  const int wave = threadIdx.x >> 6, lane = threadIdx.x & 63;
  const int row = blockIdx.x * 4 + wave;
  if (row >= E) return;
  const int half = lane >> 5, cl = lane & 31;
  const int c8 = cl * 8;
  const int beg = offs[row], end = offs[row + 1];
  float a0[8] = {0,0,0,0,0,0,0,0}, a1[8] = {0,0,0,0,0,0,0,0};
  int i = beg + half;
  for (; i + 2 < end; i += 4) {
    us8 v0 = *(const us8*)&srcb[(size_t)list[i] * 256 + c8];
    us8 v1 = *(const us8*)&srcb[(size_t)list[i + 2] * 256 + c8];
    acc8(a0, v0); acc8(a1, v1);
  }
  if (i < end) acc8(a0, *(const us8*)&srcb[(size_t)list[i] * 256 + c8]);
  float s[8];
  #pragma unroll
  for (int j = 0; j < 8; ++j) s[j] = a0[j] + a1[j];
  #pragma unroll
  for (int j = 0; j < 8; ++j) s[j] += __shfl_xor(s[j], 32);
  if (half == 0) {
    float sc = De_inv[row];
    const float* bp = (c8 < 128) ? (b1 + c8) : (b2 + c8 - 128);
    float4 bt0 = *(const float4*)bp;
    float4 bt1 = *(const float4*)(bp + 4);
    float bb[8] = {bt0.x, bt0.y, bt0.z, bt0.w, bt1.x, bt1.y, bt1.z, bt1.w};
    float al = *alphap;
    us8 ob;
    float ov[8];
    #pragma unroll
    for (int j = 0; j < 8; ++j) {
      float v = sc * s[j] + bb[j];
      v = (v >= 0.f) ? v : al * v;
      ov[j] = v; ob[j] = tob(v);
    }
    *(us8*)&e_fullb[(size_t)row * 256 + c8] = ob;
    if constexpr (SPLIT == 1) {
      float* dp = (c8 < 128) ? &d2a[(size_t)row * DD + c8] : &d2b[(size_t)row * DD + c8 - 128];
      float4 w0 = {ov[0], ov[1], ov[2], ov[3]};
      float4 w1 = {ov[4], ov[5], ov[6], ov[7]};
      *(float4*)dp = w0;
      *(float4*)(dp + 4) = w1;
    }
  }
}

__global__ __launch_bounds__(256) void gather_node_k(const u16* __restrict__ e_fullb,
                                                     const u16* __restrict__ tb,
                                                     const int* __restrict__ offs, const int* __restrict__ list,
                                                     const float* __restrict__ Dn_inv,
                                                     const float* __restrict__ b1, const float* __restrict__ b2,
                                                     const float* __restrict__ alphap,
                                                     u16* __restrict__ dstb, int N) {
  const int wave = threadIdx.x >> 6, lane = threadIdx.x & 63;
  const int row = blockIdx.x * 4 + wave;
  if (row >= N) return;
  const int half = lane >> 5, cl = lane & 31;
  const int c8 = cl * 8;
  const int beg = offs[row], end = offs[row + 1];
  float a0[8] = {0,0,0,0,0,0,0,0}, a1[8] = {0,0,0,0,0,0,0,0};
  int i = beg + half;
  for (; i + 2 < end; i += 4) {
    us8 v0 = *(const us8*)&e_fullb[(size_t)list[i] * 256 + c8];
    us8 v1 = *(const us8*)&e_fullb[(size_t)list[i + 2] * 256 + c8];
    acc8(a0, v0); acc8(a1, v1);
  }
  if (i < end) acc8(a0, *(const us8*)&e_fullb[(size_t)list[i] * 256 + c8]);
  float s[8];
  #pragma unroll
  for (int j = 0; j < 8; ++j) s[j] = a0[j] + a1[j];
  #pragma unroll
  for (int j = 0; j < 8; ++j) s[j] += __shfl_xor(s[j], 32);
  if (half == 0) {
    us8 tv = *(const us8*)&tb[(size_t)row * 256 + c8];
    const float* bp = (c8 < 128) ? (b1 + c8) : (b2 + c8 - 128);
    float4 bt0 = *(const float4*)bp;
    float4 bt1 = *(const float4*)(bp + 4);
    float bb[8] = {bt0.x, bt0.y, bt0.z, bt0.w, bt1.x, bt1.y, bt1.z, bt1.w};
    float al = *alphap;
    float sc = Dn_inv[row];
    us8 ob;
    #pragma unroll
    for (int j = 0; j < 8; ++j) {
      float sv = fb(tv[j]) + bb[j];
      sv = (sv >= 0.f) ? sv : al * sv;
      ob[j] = tob(sc * (sv + s[j]));
    }
    *(us8*)&dstb[(size_t)row * 256 + c8] = ob;
  }
}

// ================= weight prep =================

struct WPtrs { const float* p[16]; };

__global__ __launch_bounds__(256) void prep_w_k(WPtrs wp, char* dst) {
  int m = blockIdx.x >> 3, s = blockIdx.x & 7;
  const float* W = wp.p[m];
  int t = threadIdx.x;
  int n = t & 127;
  int k0 = s * 16 + (t >> 7) * 8;
  us8 vhi, vlo;
  #pragma unroll
  for (int j = 0; j < 8; ++j) {
    float x = W[(size_t)(k0 + j) * DD + n];
    u32 ux = __builtin_bit_cast(u32, x);
    float hf = __builtin_bit_cast(float, ux & 0xFFFF0000u);
    float l = x - hf;
    vhi[j] = (u16)(ux >> 16);
    vlo[j] = (u16)(__builtin_bit_cast(u32, l) >> 16);
  }
  char* base = dst + (size_t)m * 65536;
  int byte = n * 256 + k0 * 2;
  byte ^= (n & 7) << 4;
  *(us8*)(base + byte) = vhi;
  *(us8*)(base + 32768 + byte) = vlo;
}

// ================= MFMA machinery =================

__device__ __forceinline__ void stage_w(const char* gsrc, char* lds, int tid) {
  int wave = tid >> 6, lane = tid & 63;
  #pragma unroll
  for (int i = 0; i < 16; ++i) {
    int off = (wave * 16 + i) * 1024;
    __builtin_amdgcn_global_load_lds(
        (const __attribute__((address_space(1))) u32*)(gsrc + off + lane * 16),
        (__attribute__((address_space(3))) u32*)(lds + off), 16, 0, 0);
  }
}

// hi-only 32KB stage
__device__ __forceinline__ void stage_w32(const char* gsrc, char* lds, int tid) {
  int wave = tid >> 6, lane = tid & 63;
  #pragma unroll
  for (int i = 0; i < 8; ++i) {
    int off = (wave * 8 + i) * 1024;
    __builtin_amdgcn_global_load_lds(
        (const __attribute__((address_space(1))) u32*)(gsrc + off + lane * 16),
        (__attribute__((address_space(3))) u32*)(lds + off), 16, 0, 0);
  }
}

__device__ __forceinline__ void split8(const float vs[8], bh8& hi, bh8& lo) {
  #pragma unroll
  for (int j = 0; j < 8; ++j) {
    u32 u = __builtin_bit_cast(u32, vs[j]);
    float hf = __builtin_bit_cast(float, u & 0xFFFF0000u);
    float l = vs[j] - hf;
    hi[j] = (short)(u >> 16);
    lo[j] = (short)(__builtin_bit_cast(u32, l) >> 16);
  }
}

__device__ __forceinline__ void mk_afrag(const float* rowp, int koff, bh8& hi, bh8& lo) {
  float4 v0 = *(const float4*)(rowp + koff);
  float4 v1 = *(const float4*)(rowp + koff + 4);
  float vs[8] = {v0.x, v0.y, v0.z, v0.w, v1.x, v1.y, v1.z, v1.w};
  split8(vs, hi, lo);
}

// fp32-A, hi-only W (2 MFMA): exact A, quantized W
__device__ __forceinline__ void mfma_ks_hi2(const bh8& ahi, const bh8& alo, const char* Wl,
                                            int ks, int lane, f4 acc[8]) {
  const int koff0 = (lane >> 4) * 8;
  const int k2 = (ks * 32 + koff0) * 2;
  #pragma unroll
  for (int cb = 0; cb < 8; ++cb) {
    int n = cb * 16 + (lane & 15);
    int byte = (n * 256 + k2) ^ ((n & 7) << 4);
    bh8 bhiF = *(const bh8*)(Wl + byte);
    acc[cb] = __builtin_amdgcn_mfma_f32_16x16x32_bf16(ahi, bhiF, acc[cb], 0, 0, 0);
    acc[cb] = __builtin_amdgcn_mfma_f32_16x16x32_bf16(alo, bhiF, acc[cb], 0, 0, 0);
  }
}

// bf16-A exact path (2 MFMA, full W)
__device__ __forceinline__ void mfma_ks_bf(const bh8& a, const char* Wl,
                                           int ks, int lane, f4 acc[8]) {
  const int koff0 = (lane >> 4) * 8;
  const int k2 = (ks * 32 + koff0) * 2;
  #pragma unroll
  for (int cb = 0; cb < 8; ++cb) {
    int n = cb * 16 + (lane & 15);
    int byte = (n * 256 + k2) ^ ((n & 7) << 4);
    bh8 bhiF = *(const bh8*)(Wl + byte);
    bh8 bloF = *(const bh8*)(Wl + 32768 + byte);
    acc[cb] = __builtin_amdgcn_mfma_f32_16x16x32_bf16(a, bhiF, acc[cb], 0, 0, 0);
    acc[cb] = __builtin_amdgcn_mfma_f32_16x16x32_bf16(a, bloF, acc[cb], 0, 0, 0);
  }
}

// bf16-A, hi-only W (1 MFMA)
__device__ __forceinline__ void mfma_ks_bfhi(const bh8& a, const char* Wl,
                                             int ks, int lane, f4 acc[8]) {
  const int koff0 = (lane >> 4) * 8;
  const int k2 = (ks * 32 + koff0) * 2;
  #pragma unroll
  for (int cb = 0; cb < 8; ++cb) {
    int n = cb * 16 + (lane & 15);
    int byte = (n * 256 + k2) ^ ((n & 7) << 4);
    bh8 bhiF = *(const bh8*)(Wl + byte);
    acc[cb] = __builtin_amdgcn_mfma_f32_16x16x32_bf16(a, bhiF, acc[cb], 0, 0, 0);
  }
}

__device__ __forceinline__ void mfma_passS_hi2(const float* __restrict__ A, size_t astride, int acoff,
                                               const char* Wl, int rbase, int nrows, int lane, f4 acc[8]) {
  int r = rbase + (lane & 15);
  if (r >= nrows) r = nrows - 1;
  const float* rowp = A + (size_t)r * astride + acoff;
  const int koff0 = (lane >> 4) * 8;
  #pragma unroll
  for (int ks = 0; ks < 4; ++ks) {
    bh8 ahi, alo;
    mk_afrag(rowp, ks * 32 + koff0, ahi, alo);
    mfma_ks_hi2(ahi, alo, Wl, ks, lane, acc);
  }
}

__device__ __forceinline__ void mfma_passB(const u16* __restrict__ A, size_t astride, int acoff,
                                           const char* Wl, int rbase, int nrows, int lane, f4 acc[8]) {
  int r = rbase + (lane & 15);
  if (r >= nrows) r = nrows - 1;
  const u16* rowp = A + (size_t)r * astride + acoff;
  const int koff0 = (lane >> 4) * 8;
  #pragma unroll
  for (int ks = 0; ks < 4; ++ks) {
    bh8 a = __builtin_bit_cast(bh8, *(const us8*)(rowp + ks * 32 + koff0));
    mfma_ks_bf(a, Wl, ks, lane, acc);
  }
}

__device__ __forceinline__ void mfma_passB_hi(const u16* __restrict__ A, size_t astride, int acoff,
                                              const char* Wl, int rbase, int nrows, int lane, f4 acc[8]) {
  int r = rbase + (lane & 15);
  if (r >= nrows) r = nrows - 1;
  const u16* rowp = A + (size_t)r * astride + acoff;
  const int koff0 = (lane >> 4) * 8;
  #pragma unroll
  for (int ks = 0; ks < 4; ++ks) {
    bh8 a = __builtin_bit_cast(bh8, *(const us8*)(rowp + ks * 32 + koff0));
    mfma_ks_bfhi(a, Wl, ks, lane, acc);
  }
}

struct AFragB { bh8 a[4]; };

__device__ __forceinline__ void load_afragB(const u16* __restrict__ A, size_t astride, int acoff,
                                            int rbase, int nrows, int lane, AFragB& f) {
  int r = rbase + (lane & 15);
  if (r >= nrows) r = nrows - 1;
  const u16* rowp = A + (size_t)r * astride + acoff;
  const int koff0 = (lane >> 4) * 8;
  #pragma unroll
  for (int ks = 0; ks < 4; ++ks)
    f.a[ks] = __builtin_bit_cast(bh8, *(const us8*)(rowp + ks * 32 + koff0));
}

__device__ __forceinline__ void mfma_pass_fragB(const AFragB& f, const char* Wl, int lane, f4 acc[8]) {
  #pragma unroll
  for (int ks = 0; ks < 4; ++ks) mfma_ks_bf(f.a[ks], Wl, ks, lane, acc);
}

__device__ __forceinline__ void mfma_pass_fragB_hi(const AFragB& f, const char* Wl, int lane, f4 acc[8]) {
  #pragma unroll
  for (int ks = 0; ks < 4; ++ks) mfma_ks_bfhi(f.a[ks], Wl, ks, lane, acc);
}

// ---- LDS T-tile (64 rows x 128 bf16, XOR-swizzled) ----

__device__ __forceinline__ void acc_to_T(f4 acc[8], const float* bias, float al,
                                         char* Tb, int wave, int lane) {
  const int cidx = lane & 15;
  float b8[8];
  #pragma unroll
  for (int cb = 0; cb < 8; ++cb) b8[cb] = bias[cb * 16 + cidx];
  #pragma unroll
  for (int q = 0; q < 4; ++q) {
    int row = wave * 16 + (lane >> 4) * 4 + q;
    #pragma unroll
    for (int cb = 0; cb < 8; ++cb) {
      float v = acc[cb][q] + b8[cb];
      v = (v >= 0.f) ? v : al * v;
      int byte = (row * 256 + (cb * 16 + cidx) * 2) ^ ((row & 7) << 4);
      *(u16*)(Tb + byte) = tob(v);
    }
  }
}

__device__ __forceinline__ void load_fT(const char* Tb, int wave, int lane, AFragB& f) {
  const int row = wave * 16 + (lane & 15);
  const int koff0 = (lane >> 4) * 8;
  #pragma unroll
  for (int ks = 0; ks < 4; ++ks) {
    int byte = (row * 256 + (ks * 32 + koff0) * 2) ^ ((row & 7) << 4);
    f.a[ks] = __builtin_bit_cast(bh8, *(const us8*)(Tb + byte));
  }
}

// MODE 0: raw; MODE 1: +bias +prelu.  OBF: write bf16 instead of fp32.
template<int MODE, int OBF>
__device__ __forceinline__ void epilogueS(f4 acc[8], const float* bias, const float* alphap,
                                          void* outp, size_t ostride, int ocoff,
                                          int rbase, int nrows, int lane) {
  float al = 0.f;
  if constexpr (MODE == 1) al = *alphap;
  const int cidx = lane & 15;
  int rq = rbase + (lane >> 4) * 4;
  float b8[8];
  if constexpr (MODE == 1) {
    #pragma unroll
    for (int cb = 0; cb < 8; ++cb) b8[cb] = bias[cb * 16 + cidx];
  }
  #pragma unroll
  for (int q = 0; q < 4; ++q) {
    int row = rq + q;
    if (row < nrows) {
      #pragma unroll
      for (int cb = 0; cb < 8; ++cb) {
        float v = acc[cb][q];
        if constexpr (MODE == 1) { v += b8[cb]; v = (v >= 0.f) ? v : al * v; }
        if constexpr (OBF == 1) {
          u16* op = (u16*)outp + (size_t)row * ostride + ocoff + cidx;
          op[cb * 16] = tob(v);
        } else {
          float* op = (float*)outp + (size_t)row * ostride + ocoff + cidx;
          op[cb * 16] = v;
        }
      }
    }
  }
}

#define ACC_ZERO(acc) { _Pragma("unroll") for (int cb = 0; cb < 8; ++cb) acc[cb] = {0.f, 0.f, 0.f, 0.f}; }

// ================= GEMM kernels =================

// GEMM1 tile body (hi-only W, exact A): tb[blk rows] = bf16([x@W0 | xx@W4])
__device__ __forceinline__ void gemm1_body(const float* __restrict__ x, const char* W0,
                                           const float* __restrict__ xx, const char* W4,
                                           u16* __restrict__ tb, int nrows, int blk, char* Wl) {
  const int wave = threadIdx.x >> 6, lane = threadIdx.x & 63;
  const int rbase = blk * 64 + wave * 16;
  f4 acc[8];
  stage_w32(W0, Wl, threadIdx.x);
  __syncthreads();
  ACC_ZERO(acc);
  mfma_passS_hi2(x, DD, 0, Wl, rbase, nrows, lane, acc);
  epilogueS<0, 1>(acc, nullptr, nullptr, tb, 256, 0, rbase, nrows, lane);
  __syncthreads();
  stage_w32(W4, Wl, threadIdx.x);
  __syncthreads();
  ACC_ZERO(acc);
  mfma_passS_hi2(xx, DD, 0, Wl, rbase, nrows, lane, acc);
  epilogueS<0, 1>(acc, nullptr, nullptr, tb, 256, 128, rbase, nrows, lane);
}

// combo_a: blocks [0,NTg) = GEMM1 rows [0, NTg*64); rest = histogram
__global__ __launch_bounds__(256, 2) void combo_a_k(const float* __restrict__ x, const char* W0,
                                                    const float* __restrict__ xx, const char* W4,
                                                    u16* __restrict__ tb, int nrows, int NTg,
                                                    const int* __restrict__ ni, const int* __restrict__ ei,
                                                    int* cn, int* ce, int nnz) {
  __shared__ char Wl[32768];
  if ((int)blockIdx.x < NTg) {
    gemm1_body(x, W0, xx, W4, tb, nrows, blockIdx.x, Wl);
  } else {
    int nb = gridDim.x - NTg;
    int stride = nb * 256;
    for (int j = ((int)blockIdx.x - NTg) * 256 + (int)threadIdx.x; j < nnz; j += stride) {
      atomicAdd(&cn[ni[j]], 1);
      atomicAdd(&ce[ei[j]], 1);
    }
  }
}

// combo_b: blocks [0,NTg) = GEMM1 rows [blk0*64, ...); rest = XCD-local partition
__global__ __launch_bounds__(256, 2) void combo_b_k(const float* __restrict__ x, const char* W0,
                                                    const float* __restrict__ xx, const char* W4,
                                                    u16* __restrict__ tb, int nrows, int NTg, int blk0,
                                                    const int* __restrict__ ni, const int* __restrict__ ei,
                                                    int* cur_be, int* cur_bn,
                                                    u32* __restrict__ SE, u32* __restrict__ SN, int nnz) {
  __shared__ char Wl[32768];
  if ((int)blockIdx.x < NTg) {
    gemm1_body(x, W0, xx, W4, tb, nrows, blk0 + blockIdx.x, Wl);
  } else {
    int xcd;
    asm volatile("s_getreg_b32 %0, hwreg(HW_REG_XCC_ID)" : "=s"(xcd));
    xcd &= 7;
    int nb = gridDim.x - NTg;
    int stride = nb * 256;
    for (int j = ((int)blockIdx.x - NTg) * 256 + (int)threadIdx.x; j < nnz; j += stride) {
      int n = ni[j], e = ei[j];
      int pe = atomicAdd(&cur_be[(e >> 5) * 8 + xcd], 1);
      SE[pe] = ((u32)(e & 31) << 17) | (u32)n;
      int pn = atomicAdd(&cur_bn[(n >> 5) * 8 + xcd], 1);
      SN[pn] = ((u32)(n & 31) << 17) | (u32)e;
    }
  }
}

// fused hidden + GEMM3 per half, hi-only weights, H0/H1 double-buffer + dedicated T
__global__ __launch_bounds__(256, 2) void gemm_fuse_hid_k(const u16* __restrict__ thb,
                                                          const char* W20, const float* b20, const char* W21,
                                                          const char* W60, const float* b60, const char* W61,
                                                          const float* __restrict__ alphap,
                                                          u16* __restrict__ tb_out, int nrows) {
  __shared__ char Wl[81920];           // H0 [0,32K), H1 [32K,64K), T [64K,80K)
  char* H0 = Wl;
  char* H1 = Wl + 32768;
  char* Tb = Wl + 65536;
  const int wave = threadIdx.x >> 6, lane = threadIdx.x & 63;
  const int rbase = blockIdx.x * 64 + wave * 16;
  const float al = *alphap;
  f4 acc[8];
  AFragB fT;
  #pragma unroll 1
  for (int h = 0; h < 2; ++h) {
    if (h) __syncthreads();
    stage_w32(h ? W60 : W20, H0, threadIdx.x);
    __syncthreads();
    stage_w32(h ? W61 : W21, H1, threadIdx.x);   // issue-early
    ACC_ZERO(acc);
    mfma_passB_hi(thb, 256, h * 128, H0, rbase, nrows, lane, acc);
    __syncthreads();
    acc_to_T(acc, h ? b60 : b20, al, Tb, wave, lane);
    __syncthreads();
    load_fT(Tb, wave, lane, fT);
    ACC_ZERO(acc);
    mfma_pass_fragB_hi(fT, H1, lane, acc);
    epilogueS<0, 1>(acc, nullptr, nullptr, tb_out, 256, h * 128, rbase, nrows, lane);
  }
}

// encoder final (A = aggb bf16, FULL weights)
__global__ __launch_bounds__(256, 2) void enc_final_k(const u16* __restrict__ aggb, const char* W1, const float* b1_,
                                                      const char* W2, const float* b2_,
                                                      const float* __restrict__ alphap,
                                                      float* __restrict__ n1, float* __restrict__ n2,
                                                      u16* __restrict__ n1b, u16* __restrict__ n2b,
                                                      float* __restrict__ nn1, int nrows) {
  __shared__ char Wl[65536];
  const int wave = threadIdx.x >> 6, lane = threadIdx.x & 63;
  const int rbase = blockIdx.x * 64 + wave * 16;
  const int cidx = lane & 15;
  f4 acc[8];
  float al = *alphap;
  #pragma unroll 1
  for (int h = 0; h < 2; ++h) {
    if (h) __syncthreads();
    stage_w(h ? W2 : W1, Wl, threadIdx.x);
    __syncthreads();
    const float* bp = h ? b2_ : b1_;
    float* nout = h ? n2 : n1;
    u16* nbout = h ? n2b : n1b;
    float b8[8];
    #pragma unroll
    for (int cb = 0; cb < 8; ++cb) b8[cb] = bp[cb * 16 + cidx];
    ACC_ZERO(acc);
    mfma_passB(aggb, 256, h * 128, Wl, rbase, nrows, lane, acc);
    int rq = rbase + (lane >> 4) * 4;
    #pragma unroll
    for (int q = 0; q < 4; ++q) {
      int row = rq + q;
      if (row < nrows) {
        float* op = nout + (size_t)row * DD + cidx;
        float* op2 = nn1 + (size_t)row * 256 + h * 128 + cidx;
        u16* op3 = nbout + (size_t)row * DD + cidx;
        #pragma unroll
        for (int cb = 0; cb < 8; ++cb) {
          float v = acc[cb][q] + b8[cb];
          v = (v >= 0.f) ? v : al * v;
          op[cb * 16] = v;
          op2[cb * 16] = v;
          op3[cb * 16] = tob(v);
        }
      }
    }
  }
}

// fully-fused decoder (FULL weights): 1 tile, y = n-stream, serial d-stream loop.
__global__ __launch_bounds__(256, 2) void dec_fused_k(const u16* __restrict__ n1b, const u16* __restrict__ n2b,
                                                      const u16* __restrict__ aggb,
                                                      const char* Wx10, const char* We10, const float* b1_0,
                                                      const char* Wx11, const char* We11, const float* b1_1,
                                                      const char* Wx20, const char* We20, const float* b2_0,
                                                      const char* Wx21, const char* We21, const float* b2_1,
                                                      const float* __restrict__ alphap,
                                                      float* __restrict__ x11, float* __restrict__ x22,
                                                      float* __restrict__ x12, float* __restrict__ x21,
                                                      int nrows) {
  __shared__ char Wl[65536];
  const int y = blockIdx.y;
  const u16* xb = y ? n2b : n1b;
  float* od1 = y ? x12 : x11;
  float* od2 = y ? x21 : x22;
  const int acoff = y * 128;
  const int wave = threadIdx.x >> 6, lane = threadIdx.x & 63;
  const int rbase = blockIdx.x * 64 + wave * 16;
  const float al = *alphap;
  AFragB fx, fa, fT;
  load_afragB(xb, DD, 0, rbase, nrows, lane, fx);
  load_afragB(aggb, 256, acoff, rbase, nrows, lane, fa);
  f4 acc[8];
  #pragma unroll 1
  for (int s = 0; s < 2; ++s) {
    const char* Wx0 = s ? Wx20 : Wx10;
    const char* We0 = s ? We20 : We10;
    const char* Wx1 = s ? Wx21 : Wx11;
    const char* We1 = s ? We21 : We11;
    const float* b0 = s ? b2_0 : b1_0;
    const float* b1 = s ? b2_1 : b1_1;
    float* out = s ? od2 : od1;
    if (s) __syncthreads();
    stage_w(Wx0, Wl, threadIdx.x);
    __syncthreads();
    ACC_ZERO(acc);
    mfma_pass_fragB(fx, Wl, lane, acc);
    __syncthreads();
    stage_w(We0, Wl, threadIdx.x);
    __syncthreads();
    mfma_pass_fragB(fa, Wl, lane, acc);
    __syncthreads();
    acc_to_T(acc, b0, al, Wl, wave, lane);
    __syncthreads();
    load_fT(Wl, wave, lane, fT);
    __syncthreads();
    stage_w(Wx1, Wl, threadIdx.x);
    __syncthreads();
    ACC_ZERO(acc);
    mfma_pass_fragB(fT, Wl, lane, acc);
    __syncthreads();
    stage_w(We1, Wl, threadIdx.x);
    __syncthreads();
    mfma_pass_fragB(fa, Wl, lane, acc);
    epilogueS<1, 0>(acc, b1, alphap, out, DD, 0, rbase, nrows, lane);
  }
}

// ================= host =================

extern "C" void kernel_launch(void* const* d_in, const int* in_sizes, int n_in,
                              void* d_out, int out_size, void* d_ws, size_t ws_size,
                              hipStream_t stream) {
  const float* x        = (const float*)d_in[0];
  const float* xx       = (const float*)d_in[1];
  const int*   node_idx = (const int*)d_in[2];
  const int*   edge_idx = (const int*)d_in[3];
  const float* alphap   = (const float*)d_in[6];
  const float* e1_Wn2e  = (const float*)d_in[7];
  const float* e1_bn2e  = (const float*)d_in[8];
  const float* e1_We2n  = (const float*)d_in[9];
  const float* e1_be2n  = (const float*)d_in[10];
  const float* e2_Wn2e  = (const float*)d_in[11];
  const float* e2_bn2e  = (const float*)d_in[12];
  const float* e2_We2n  = (const float*)d_in[13];
  const float* e2_be2n  = (const float*)d_in[14];
  const float* d1_We    = (const float*)d_in[15];
  const float* d1_Wx    = (const float*)d_in[16];
  const float* d1_b     = (const float*)d_in[17];
  const float* d2_We    = (const float*)d_in[18];
  const float* d2_Wx    = (const float*)d_in[19];
  const float* d2_b     = (const float*)d_in[20];

  const int N   = in_sizes[0] / DD;
  const int NNZ = in_sizes[2];
  const int E   = (out_size - 1024 * N) / 256;
  const int NBE = (E + 31) >> 5;
  const int NBN = (N + 31) >> 5;
  const int NCHN = (N + 1023) >> 10;
  const int NCHE = (E + 1023) >> 10;

  // ---- d_out slot map ----
  float* out  = (float*)d_out;
  float* nn1  = out;
  float* n1   = out + (size_t)N * 256;
  float* e1o  = n1 + (size_t)N * DD;
  float* n2   = e1o + (size_t)E * DD;
  float* e2o  = n2 + (size_t)N * DD;
  float* x11  = e2o + (size_t)E * DD;
  float* x21  = x11 + (size_t)N * DD;
  float* x12  = x21 + (size_t)N * DD;
  float* x22  = x12 + (size_t)N * DD;

  // ---- workspace carve ----
  size_t off = 0;
  char* w0 = (char*)d_ws;
  auto carve = [&](size_t bytes) -> void* {
    void* p = (void*)(w0 + off);
    off += (bytes + 255) & ~(size_t)255;
    return p;
  };
  int* cn      = (int*)carve((size_t)N * 4);
  int* ce      = (int*)carve((size_t)E * 4);
  int* offs_n  = (int*)carve((size_t)(N + 1) * 4);
  int* offs_e  = (int*)carve((size_t)(E + 1) * 4);
  int* part    = (int*)carve((size_t)(NCHN + NCHE) * 4);
  int* listN   = (int*)carve((size_t)NNZ * 4);
  int* listE   = (int*)carve((size_t)NNZ * 4);
  float* Dn_inv = (float*)carve((size_t)N * 4);
  float* De_inv = (float*)carve((size_t)E * 4);
  char* Wprep  = (char*)carve((size_t)16 * 65536);
  u16* tb      = (u16*)carve((size_t)N * 256 * 2);
  u16* e_fullb = (u16*)carve((size_t)E * 256 * 2);
  u16* thb     = (u16*)carve((size_t)N * 256 * 2);
  u16* aggb    = (u16*)carve((size_t)N * 256 * 2);
  u16* n1b     = (u16*)carve((size_t)N * DD * 2);
  u16* n2b     = (u16*)carve((size_t)N * DD * 2);
  int* cur_be  = (int*)carve((size_t)NBE * 8 * 4);
  int* cur_bn  = (int*)carve((size_t)NBN * 8 * 4);
  u32* SE      = (u32*)carve((size_t)NNZ * 8 * 4);
  u32* SN      = (u32*)carve((size_t)NNZ * 8 * 4);

  // ---- weight prep table ----
  WPtrs wp;
  wp.p[0] = e1_Wn2e;  wp.p[1] = e1_Wn2e + DD * DD;
  wp.p[2] = e1_We2n;  wp.p[3] = e1_We2n + DD * DD;
  wp.p[4] = e2_Wn2e;  wp.p[5] = e2_Wn2e + DD * DD;
  wp.p[6] = e2_We2n;  wp.p[7] = e2_We2n + DD * DD;
  wp.p[8] = d1_We;    wp.p[9] = d1_We + DD * DD;
  wp.p[10] = d1_Wx;   wp.p[11] = d1_Wx + DD * DD;
  wp.p[12] = d2_We;   wp.p[13] = d2_We + DD * DD;
  wp.p[14] = d2_Wx;   wp.p[15] = d2_Wx + DD * DD;
  auto WP = [&](int i) -> const char* { return Wprep + (size_t)i * 65536; };

  const int thr = 256;
  const int gMax = ((N > E ? N : E) + thr - 1) / thr;
  const int NT = (N + 63) / 64;
  const int NTa = NT / 2;              // GEMM1 rows [0, NTa*64) in combo_a
  const int NTb = NT - NTa;            // rest in combo_b
  const int HB = 512;                  // histogram blocks
  const int PB = 512;                  // partition blocks
  const int gGatE = (E + 3) / 4;
  const int gGatN = (N + 3) / 4;

  prep_w_k<<<128, 256, 0, stream>>>(wp, Wprep);
  init_counts_k<<<gMax, thr, 0, stream>>>(cn, ce, N, E);
  // GEMM1 first half ∥ histogram
  combo_a_k<<<NTa + HB, 256, 0, stream>>>(x, WP(0), xx, WP(4), tb, N, NTa,
                                          node_idx, edge_idx, cn, ce, NNZ);
  scan_partials_k<<<NCHN + NCHE, 256, 0, stream>>>(cn, ce, part, NCHN, N, NCHE, E);
  scan_apply_k<<<NCHN + NCHE, 256, 0, stream>>>(cn, ce, part, offs_n, offs_e,
                                                Dn_inv, De_inv, cur_bn, cur_be,
                                                NCHN, N, NCHE, E, NBN, NBE);
  // GEMM1 second half ∥ XCD-local partition
  combo_b_k<<<NTb + PB, 256, 0, stream>>>(x, WP(0), xx, WP(4), tb, N, NTb, NTa,
                                          node_idx, edge_idx, cur_be, cur_bn, SE, SN, NNZ);
  scatter_both_k<<<NBE + NBN, 256, 0, stream>>>(SE, offs_e, cur_be, listE, E, NBE,
                                                SN, offs_n, cur_bn, listN, N);

  // ---- fused dual-encoder ----
  gather_edge_k<0><<<gGatE, 256, 0, stream>>>(tb, offs_e, listE, De_inv, e1_bn2e, e2_bn2e,
                                              alphap, e_fullb, nullptr, nullptr, E);
  gather_node_k<<<gGatN, 256, 0, stream>>>(e_fullb, tb, offs_n, listN, Dn_inv, e1_bn2e, e2_bn2e,
                                           alphap, thb, N);
  gemm_fuse_hid_k<<<NT, 256, 0, stream>>>(thb, WP(2), e1_be2n, WP(1),
                                          WP(6), e2_be2n, WP(5), alphap, tb, N);
  gather_edge_k<1><<<gGatE, 256, 0, stream>>>(tb, offs_e, listE, De_inv, e1_bn2e + DD, e2_bn2e + DD,
                                              alphap, e_fullb, e1o, e2o, E);
  gather_node_k<<<gGatN, 256, 0, stream>>>(e_fullb, tb, offs_n, listN, Dn_inv, e1_bn2e + DD, e2_bn2e + DD,
                                           alphap, aggb, N);
  enc_final_k<<<NT, 256, 0, stream>>>(aggb, WP(3), e1_be2n + DD, WP(7), e2_be2n + DD,
                                      alphap, n1, n2, n1b, n2b, nn1, N);

  // ---- fully-fused decoders ----
  dim3 gDec(NT, 2);
  dec_fused_k<<<gDec, 256, 0, stream>>>(n1b, n2b, aggb,
                                        WP(10), WP(8), d1_b, WP(11), WP(9), d1_b + DD,
                                        WP(14), WP(12), d2_b, WP(15), WP(13), d2_b + DD,
                                        alphap, x11, x22, x12, x21, N);
}